// Round 1
// baseline (888.957 us; speedup 1.0000x reference)
//
#include <hip/hip_runtime.h>
#include <cmath>

#define DI __device__ __forceinline__

constexpr int B_=2, S_=2048, E_=1024, H_=1344, NH_=4, DH_=336;
constexpr int BS_=B_*S_, H2_=2*H_;
constexpr int NG_=B_*NH_*S_;   // 16384

constexpr size_t N_X=(size_t)BS_*E_;
constexpr size_t N_WUP=(size_t)E_*H2_;
constexpr size_t N_WDN=(size_t)H_*E_;
constexpr size_t N_BSH=(size_t)BS_*H_;
constexpr size_t N_BSH2=(size_t)BS_*H2_;
constexpr size_t N_WH=5376, N_WG=16128, N_CK=4*H_;

// ---- ws layout (floats); identical to prior passing rounds ----
constexpr size_t O_IGB = 64;
constexpr size_t O_LOGF= O_IGB + NG_;
constexpr size_t O_AB  = O_LOGF+ NG_;
constexpr size_t O_MB  = O_AB  + NG_;
constexpr size_t O_MTB = O_MB  + NG_;
constexpr size_t O_CK  = O_MTB + NG_;
constexpr size_t O_CB  = O_CK  + N_CK;
constexpr size_t O_WQ  = O_CB  + H_;
constexpr size_t O_WK  = O_WQ  + N_WH;
constexpr size_t O_WV  = O_WK  + N_WH;
constexpr size_t O_WIG = O_WV  + N_WH;
constexpr size_t O_BIG = O_WIG + N_WG;
constexpr size_t O_WFG = O_BIG + 16;
constexpr size_t O_BFG = O_WFG + N_WG;
constexpr size_t O_LNW = O_BFG + 16;
constexpr size_t O_SKP = O_LNW + H_;
constexpr size_t O_FX  = O_SKP + H_;
constexpr size_t O_FWUP= O_FX  + N_X;
constexpr size_t O_FWDN= O_FWUP+ N_WUP;
constexpr size_t O_XIN = O_FWDN+ N_WDN;
constexpr size_t O_ACT = O_XIN + N_BSH2;
constexpr size_t O_QB  = O_ACT + N_BSH;
constexpr size_t O_KB  = O_QB  + N_BSH;
constexpr size_t O_VB  = O_KB  + N_BSH;
constexpr size_t O_HOUT= O_VB  + N_BSH;

// khi/klo: [head][tile=t/16][dc=0..10][l][8] bf16 (B-frag 16x16x32)
constexpr size_t KSPLIT_SHORTS=(size_t)8*128*11*64*8;  // 5,767,168
// vTf: [head][tc=t/32][ntg=0..21][l][8] bf16; n==336 -> 1.0 (rowsum), n>336 -> 0
constexpr size_t VT_SHORTS=(size_t)8*64*22*64*8;       // 5,767,168

typedef __attribute__((ext_vector_type(8))) short bf16x8;
typedef __attribute__((ext_vector_type(4))) float f32x4;

DI float bf2f(unsigned int u){union{unsigned int i;float f;}v;v.i=(u&0xffffu)<<16;return v.f;}
DI unsigned short f2bf(float f){union{float f;unsigned int i;}v;v.f=f;unsigned int x=v.i;
  return (unsigned short)((x+0x7fffu+((x>>16)&1u))>>16);}
DI float siluf(float x){return x/(1.f+expf(-x));}
DI float logsigf(float x){return (x>=0.f)?-log1pf(expf(-x)):x-log1pf(expf(x));}
DI void load4(const float* p, float* d){float4 v=*reinterpret_cast<const float4*>(p);
  d[0]=v.x;d[1]=v.y;d[2]=v.z;d[3]=v.w;}

// ---- dtype detect (fp32 proven; keep the guard) ----
__global__ __launch_bounds__(256) void detect_k(const unsigned short* __restrict__ xraw,
                                                int* __restrict__ flag){
  __shared__ int cnt_s;
  if(threadIdx.x==0) cnt_s=0;
  __syncthreads();
  int c=0;
  for(int i=threadIdx.x;i<2048;i+=256){
    const unsigned e=(xraw[i]>>7)&0xFFu;
    if(e>=0x90u) c++;
  }
  atomicAdd(&cnt_s,c);
  __syncthreads();
  if(threadIdx.x==0) *flag=(cnt_s>16)?0:1;
}

__global__ __launch_bounds__(256) void convert_k(const void* __restrict__ src,
                                                 float* __restrict__ dst,int n,
                                                 const int* __restrict__ flag){
  const int i=blockIdx.x*256+threadIdx.x;
  if(i>=n) return;
  if(*flag) dst[i]=bf2f(((const unsigned short*)src)[i]);
  else      dst[i]=((const float*)src)[i];
}

// ============================================================================
// A-fragment prep
// ============================================================================
__global__ __launch_bounds__(256) void aprep_k(const void* __restrict__ src,
                                               const int* __restrict__ flag,
                                               int kcn,int ldk,int total,
                                               unsigned short* __restrict__ hi,
                                               unsigned short* __restrict__ lo){
  const int slot=blockIdx.x*256+threadIdx.x;
  if(slot>=total) return;
  const int l=slot&63, rest=slot>>6;
  const int kc=rest%kcn, mt=rest/kcn;
  const int row=mt*16+(l&15), k0=kc*32+(l>>4)*8;
  const int fl=flag?*flag:0;
  float v[8];
  if(fl){
    const unsigned short* s=(const unsigned short*)src+(size_t)row*ldk+k0;
    const uint4 u=*reinterpret_cast<const uint4*>(s);
    v[0]=bf2f(u.x);v[1]=bf2f(u.x>>16);v[2]=bf2f(u.y);v[3]=bf2f(u.y>>16);
    v[4]=bf2f(u.z);v[5]=bf2f(u.z>>16);v[6]=bf2f(u.w);v[7]=bf2f(u.w>>16);
  }else{
    const float* s=(const float*)src+(size_t)row*ldk+k0;
    load4(s,v); load4(s+4,v+4);
  }
  unsigned short h8[8], l8[8];
#pragma unroll
  for(int j=0;j<8;j++){ h8[j]=f2bf(v[j]); l8[j]=f2bf(v[j]-bf2f(h8[j])); }
  uint4 ph,pl;
  ph.x=(unsigned)h8[0]|((unsigned)h8[1]<<16); ph.y=(unsigned)h8[2]|((unsigned)h8[3]<<16);
  ph.z=(unsigned)h8[4]|((unsigned)h8[5]<<16); ph.w=(unsigned)h8[6]|((unsigned)h8[7]<<16);
  pl.x=(unsigned)l8[0]|((unsigned)l8[1]<<16); pl.y=(unsigned)l8[2]|((unsigned)l8[3]<<16);
  pl.z=(unsigned)l8[4]|((unsigned)l8[5]<<16); pl.w=(unsigned)l8[6]|((unsigned)l8[7]<<16);
  *reinterpret_cast<uint4*>(&hi[(size_t)slot*8])=ph;
  *reinterpret_cast<uint4*>(&lo[(size_t)slot*8])=pl;
}

// ============================================================================
// B-fragment prep
// ============================================================================
__global__ __launch_bounds__(256) void bprep_k(const void* __restrict__ src,
                                               const int* __restrict__ flag,
                                               int kcn,int ldn,int total,
                                               unsigned short* __restrict__ hi,
                                               unsigned short* __restrict__ lo){
  const int slot=blockIdx.x*256+threadIdx.x;
  if(slot>=total) return;
  const int l=slot&63, rest=slot>>6;
  const int kc=rest%kcn, nt=rest/kcn;
  const int col=nt*16+(l&15), row0=kc*32+(l>>4)*8;
  const int fl=flag?*flag:0;
  float v[8];
  if(fl){
    const unsigned short* s=(const unsigned short*)src;
#pragma unroll
    for(int j=0;j<8;j++) v[j]=bf2f(s[(size_t)(row0+j)*ldn+col]);
  }else{
    const float* s=(const float*)src;
#pragma unroll
    for(int j=0;j<8;j++) v[j]=s[(size_t)(row0+j)*ldn+col];
  }
  unsigned short h8[8], l8[8];
#pragma unroll
  for(int j=0;j<8;j++){ h8[j]=f2bf(v[j]); l8[j]=f2bf(v[j]-bf2f(h8[j])); }
  uint4 ph,pl;
  ph.x=(unsigned)h8[0]|((unsigned)h8[1]<<16); ph.y=(unsigned)h8[2]|((unsigned)h8[3]<<16);
  ph.z=(unsigned)h8[4]|((unsigned)h8[5]<<16); ph.w=(unsigned)h8[6]|((unsigned)h8[7]<<16);
  pl.x=(unsigned)l8[0]|((unsigned)l8[1]<<16); pl.y=(unsigned)l8[2]|((unsigned)l8[3]<<16);
  pl.z=(unsigned)l8[4]|((unsigned)l8[5]<<16); pl.w=(unsigned)l8[6]|((unsigned)l8[7]<<16);
  *reinterpret_cast<uint4*>(&hi[(size_t)slot*8])=ph;
  *reinterpret_cast<uint4*>(&lo[(size_t)slot*8])=pl;
}

// ============================================================================
// MFMA GEMM: 128x64 tile, split-bf16 3-chain, fp32 acc
// ============================================================================
__global__ __launch_bounds__(256) void gemm_mfma_k(
    const unsigned short* __restrict__ Ahi, const unsigned short* __restrict__ Alo,
    const unsigned short* __restrict__ Bhi, const unsigned short* __restrict__ Blo,
    void* __restrict__ C, const int* __restrict__ flag, int kcn, int ldc){
  const int t=threadIdx.x, w=t>>6, l=t&63, lm=l&15, quad=l>>4;
  const int bn=blockIdx.x*64, bm=blockIdx.y*128;
  const int mt0=(bm>>4)+w, mt1=mt0+4;
  const size_t a0=((size_t)mt0*kcn)*512+(size_t)l*8;
  const size_t a1=((size_t)mt1*kcn)*512+(size_t)l*8;
  const size_t b0=((size_t)(bn>>4)*kcn)*512+(size_t)l*8;
  f32x4 acc[2][4];
#pragma unroll
  for(int g=0;g<2;g++)
#pragma unroll
    for(int nt=0;nt<4;nt++) acc[g][nt]={0.f,0.f,0.f,0.f};
  for(int kc=0;kc<kcn;kc++){
    const bf16x8 ah0=*reinterpret_cast<const bf16x8*>(&Ahi[a0+(size_t)kc*512]);
    const bf16x8 al0=*reinterpret_cast<const bf16x8*>(&Alo[a0+(size_t)kc*512]);
    const bf16x8 ah1=*reinterpret_cast<const bf16x8*>(&Ahi[a1+(size_t)kc*512]);
    const bf16x8 al1=*reinterpret_cast<const bf16x8*>(&Alo[a1+(size_t)kc*512]);
#pragma unroll
    for(int nt=0;nt<4;nt++){
      const size_t bo=b0+((size_t)nt*kcn+kc)*512;
      const bf16x8 bh=*reinterpret_cast<const bf16x8*>(&Bhi[bo]);
      const bf16x8 bl=*reinterpret_cast<const bf16x8*>(&Blo[bo]);
      acc[0][nt]=__builtin_amdgcn_mfma_f32_16x16x32_bf16(ah0,bh,acc[0][nt],0,0,0);
      acc[0][nt]=__builtin_amdgcn_mfma_f32_16x16x32_bf16(al0,bh,acc[0][nt],0,0,0);
      acc[0][nt]=__builtin_amdgcn_mfma_f32_16x16x32_bf16(ah0,bl,acc[0][nt],0,0,0);
      acc[1][nt]=__builtin_amdgcn_mfma_f32_16x16x32_bf16(ah1,bh,acc[1][nt],0,0,0);
      acc[1][nt]=__builtin_amdgcn_mfma_f32_16x16x32_bf16(al1,bh,acc[1][nt],0,0,0);
      acc[1][nt]=__builtin_amdgcn_mfma_f32_16x16x32_bf16(ah1,bl,acc[1][nt],0,0,0);
    }
  }
  const int bf=flag?*flag:0;
#pragma unroll
  for(int g=0;g<2;g++)
#pragma unroll
    for(int nt=0;nt<4;nt++)
#pragma unroll
      for(int r=0;r<4;r++){
        const size_t idx=(size_t)(bm+g*64+w*16+quad*4+r)*ldc+bn+nt*16+lm;
        if(bf) ((unsigned short*)C)[idx]=f2bf(acc[g][nt][r]);
        else   ((float*)C)[idx]=acc[g][nt][r];
      }
}

// ---- causal depthwise conv(K=4)+bias -> SiLU ----
__global__ __launch_bounds__(256) void conv_act_k(const float* __restrict__ xin,
                                                  const float* __restrict__ ck,
                                                  const float* __restrict__ cb,
                                                  float* __restrict__ act){
  const int i=blockIdx.x*256+threadIdx.x;
  if(i>=(int)N_BSH) return;
  const int bs=i/H_, h=i-bs*H_;
  const int b=bs/S_, s=bs-b*S_;
  float xc=cb[h];
#pragma unroll
  for(int w=0;w<4;w++){
    const int sr=s-3+w;
    if(sr>=0) xc+=xin[(size_t)(b*S_+sr)*H2_+h]*ck[w*H_+h];
  }
  act[(size_t)bs*H_+h]=siluf(xc);
}

// ---- headwise q/k/v ----
__global__ __launch_bounds__(256) void qkv_k(const float* __restrict__ act,
                                             const float* __restrict__ xin,
                                             const float* __restrict__ Wq,
                                             const float* __restrict__ Wk,
                                             const float* __restrict__ Wv,
                                             float* __restrict__ qb,float* __restrict__ kb,
                                             float* __restrict__ vb){
  const int i=blockIdx.x*256+threadIdx.x;
  if(i>=(int)N_BSH) return;
  const int bs=i/H_, h=i-bs*H_;
  const int b=bs/S_, s=bs-b*S_;
  const int ph=h>>2, o=h&3, base=ph*4;
  float q=0.f,k=0.f,v=0.f;
#pragma unroll
  for(int d=0;d<4;d++){
    const float a=act[(size_t)bs*H_+base+d];
    const float x=xin[(size_t)bs*H2_+base+d];
    q+=a*Wq[ph*16+d*4+o];
    k+=a*Wk[ph*16+d*4+o];
    v+=x*Wv[ph*16+d*4+o];
  }
  const int nh=h/DH_, dh=h-nh*DH_;
  const size_t off=((size_t)(b*NH_+nh)*S_+s)*DH_+dh;
  qb[off]=q; kb[off]=k; vb[off]=v;
}

// ---- gate pre-activations: 8 lanes per output + shfl reduce ----
__global__ __launch_bounds__(256) void gates_k(const float* __restrict__ qb,
                                               const float* __restrict__ kb,
                                               const float* __restrict__ vb,
                                               const float* __restrict__ Wig,
                                               const float* __restrict__ big,
                                               const float* __restrict__ Wfg,
                                               const float* __restrict__ bfg,
                                               float* __restrict__ igb,float* __restrict__ logfb){
  const int i=blockIdx.x*256+threadIdx.x;
  if(i>=BS_*NH_*8) return;
  const int sub=i&7, out=i>>3;
  const int n=out&3, bs=out>>2;
  const int b=bs/S_, s=bs-b*S_;
  const int d0=sub*42;                       // 336/8 = 42 contiguous per lane
  float sig=0.f,sfg=0.f;
  for(int nh=0;nh<NH_;nh++){
    const size_t rb=((size_t)(b*NH_+nh)*S_+s)*DH_;
    for(int dh=d0;dh<d0+42;dh++){
      const int h=nh*DH_+dh;
      const float q=qb[rb+dh], k=kb[rb+dh], v=vb[rb+dh];
      sig+=q*Wig[h*4+n]+k*Wig[(H_+h)*4+n]+v*Wig[(2*H_+h)*4+n];
      sfg+=q*Wfg[h*4+n]+k*Wfg[(H_+h)*4+n]+v*Wfg[(2*H_+h)*4+n];
    }
  }
#pragma unroll
  for(int m=1;m<8;m<<=1){ sig+=__shfl_xor(sig,m); sfg+=__shfl_xor(sfg,m); }
  if(sub==0){
    const size_t off=(size_t)(b*NH_+n)*S_+s;
    igb[off]=sig+big[n];
    logfb[off]=logsigf(sfg+bfg[n]);
  }
}

// ---- K prep: split fp32 K into hi/lo bf16, MFMA B-fragment tile layout ----
__global__ __launch_bounds__(256) void kprep_k(const float* __restrict__ kb,
                                               unsigned short* __restrict__ khi,
                                               unsigned short* __restrict__ klo){
  const int blk=blockIdx.x;                 // 8 heads * 128 t-tiles
  const int head=blk>>7, tt=blk&127;
  const size_t obase=(size_t)blk*11*512;
  for(int slot=threadIdx.x; slot<704; slot+=256){
    const int dc=slot>>6, ll=slot&63, quad=ll>>4, lm=ll&15;
    const int tg=tt*16+lm, dbase=dc*32+quad*8;
    float v[8];
    if(dbase<336){
      load4(&kb[((size_t)head*S_+tg)*DH_+dbase],v);
      load4(&kb[((size_t)head*S_+tg)*DH_+dbase+4],v+4);
    } else { for(int j=0;j<8;j++) v[j]=0.f; }
    unsigned short hi8[8], lo8[8];
#pragma unroll
    for(int j=0;j<8;j++){
      hi8[j]=f2bf(v[j]);
      lo8[j]=f2bf(v[j]-bf2f(hi8[j]));
    }
    const size_t o=obase+(size_t)(dc*64+ll)*8;
    uint4 ph, pl;
    ph.x=(unsigned)hi8[0]|((unsigned)hi8[1]<<16); ph.y=(unsigned)hi8[2]|((unsigned)hi8[3]<<16);
    ph.z=(unsigned)hi8[4]|((unsigned)hi8[5]<<16); ph.w=(unsigned)hi8[6]|((unsigned)hi8[7]<<16);
    pl.x=(unsigned)lo8[0]|((unsigned)lo8[1]<<16); pl.y=(unsigned)lo8[2]|((unsigned)lo8[3]<<16);
    pl.z=(unsigned)lo8[4]|((unsigned)lo8[5]<<16); pl.w=(unsigned)lo8[6]|((unsigned)lo8[7]<<16);
    *reinterpret_cast<uint4*>(&khi[o])=ph;
    *reinterpret_cast<uint4*>(&klo[o])=pl;
  }
}

// ---- V prep: V^T bf16 in MFMA B-fragment tile layout; col 336 = ones ----
__global__ __launch_bounds__(256) void vprep_k(const float* __restrict__ vb,
                                               unsigned short* __restrict__ vTf){
  const int blk=blockIdx.x;                 // 8 heads * 64 t-chunks
  const int head=blk>>6, tc=blk&63;
  const size_t obase=(size_t)blk*22*512;
  for(int slot=threadIdx.x; slot<1408; slot+=256){
    const int ntg=slot>>6, ll=slot&63, quad=ll>>4, lm=ll&15;
    const int n=ntg*16+lm, t0=tc*32+quad*8;
    unsigned short h8[8];
#pragma unroll
    for(int j=0;j<8;j++){
      float val;
      if(n<336)       val=vb[((size_t)head*S_+t0+j)*DH_+n];
      else if(n==336) val=1.f;
      else            val=0.f;
      h8[j]=f2bf(val);
    }
    uint4 pk;
    pk.x=(unsigned)h8[0]|((unsigned)h8[1]<<16); pk.y=(unsigned)h8[2]|((unsigned)h8[3]<<16);
    pk.z=(unsigned)h8[4]|((unsigned)h8[5]<<16); pk.w=(unsigned)h8[6]|((unsigned)h8[7]<<16);
    *reinterpret_cast<uint4*>(&vTf[obase+(size_t)(ntg*64+ll)*8])=pk;
  }
}

// ---- parallel per-head scan ----
__global__ __launch_bounds__(256) void scan_k(const float* __restrict__ igb,
                                              const float* __restrict__ logfb,
                                              float* __restrict__ ab,float* __restrict__ Mb,
                                              float* __restrict__ mtb){
  const int head=blockIdx.x, t=threadIdx.x;
  __shared__ float sh[256];
  const float* lf=logfb+(size_t)head*S_;
  const float* ig=igb+(size_t)head*S_;
  float lc[8];
  float run=0.f;
#pragma unroll
  for(int i=0;i<8;i++){ run+=lf[t*8+i]; lc[i]=run; }
  sh[t]=run;
  for(int st=1;st<256;st<<=1){
    __syncthreads();
    const float v=(t>=st)?sh[t-st]:0.f;
    __syncthreads();
    sh[t]+=v;
  }
  __syncthreads();
  const float off=(t==0)?0.f:sh[t-1];
  __syncthreads();
  float av[8],mv[8],cv[8];
  float mrun=-1e30f;
#pragma unroll
  for(int i=0;i<8;i++){
    cv[i]=off+lc[i];
    av[i]=ig[t*8+i]-cv[i];
    mrun=fmaxf(mrun,av[i]);
    mv[i]=mrun;
  }
  sh[t]=mrun;
  for(int st=1;st<256;st<<=1){
    __syncthreads();
    const float v=(t>=st)?sh[t-st]:-1e30f;
    __syncthreads();
    sh[t]=fmaxf(sh[t],v);
  }
  __syncthreads();
  const float moff=(t==0)?-1e30f:sh[t-1];
#pragma unroll
  for(int i=0;i<8;i++){
    const float Mi=fmaxf(moff,mv[i]);
    const size_t j=(size_t)head*S_+t*8+i;
    ab[j]=av[i]; Mb[j]=Mi; mtb[j]=cv[i]+Mi;
  }
}

// ============================================================================
// mLSTM v7 — 32-row ownership blocks, NO atomics, fused groupnorm epilogue.
// Block = (head, 32-row tile). Waves: (row-half, chunk-parity). Parity
// partials combined through LDS; par==0 waves normalize + store hout.
// ============================================================================
__global__ __launch_bounds__(256) void mlstm2_k(
    const float* __restrict__ qb, const unsigned short* __restrict__ khi,
    const unsigned short* __restrict__ klo, const unsigned short* __restrict__ vTf,
    const float* __restrict__ ab, const float* __restrict__ Mb,
    const float* __restrict__ mtb, const float* __restrict__ lnw,
    float* __restrict__ hout){
  const int bid=blockIdx.x;
  const int head=bid&7;                     // XCD-pin heuristic
  const int st=63-(bid>>3);                 // heavy tiles first
  const int s0=st*32;
  const int nch=st+1;                       // causal 32-col chunks
  const int t=threadIdx.x, w=t>>6, l=t&63, lm=l&15, quad=l>>4;
  const int rw=w&1, par=w>>1;
  const int ws0=s0+rw*16;

  __shared__ short Sc[4][16][40];           // per-wave S buffer (no barrier)
  __shared__ float comb[2][64][89];         // parity combine (padded vs banks)

  const size_t hb=(size_t)head*S_;
  bf16x8 qh[11], ql[11];
  {
    const float* qrow=qb+(hb+ws0+lm)*DH_;
#pragma unroll
    for(int dc=0;dc<11;dc++){
      const int dbase=dc*32+quad*8;
      float v[8];
      if(dbase<336){ load4(qrow+dbase,v); load4(qrow+dbase+4,v+4); }
      else { for(int j=0;j<8;j++) v[j]=0.f; }
#pragma unroll
      for(int j=0;j<8;j++){
        const unsigned short h=f2bf(v[j]);
        qh[dc][j]=(short)h;
        ql[dc][j]=(short)f2bf(v[j]-bf2f(h));
      }
    }
  }
  float Mr[4];
#pragma unroll
  for(int r=0;r<4;r++) Mr[r]=Mb[hb+ws0+quad*4+r];

  f32x4 accO[22];
#pragma unroll
  for(int n=0;n<22;n++) accO[n]={0.f,0.f,0.f,0.f};

  const float scale=0.05455447256f;         // 336^-0.5

  for(int c=par;c<nch;c+=2){
    const int t0=c<<5;
    const float al0=ab[hb+t0+lm];
    const float al1=ab[hb+t0+16+lm];
#pragma unroll
    for(int tt=0;tt<2;tt++){
      const size_t kb0=(((size_t)head*128+(size_t)(c*2+tt))*11)*512+(size_t)l*8;
      f32x4 a0={0,0,0,0}, a1={0,0,0,0}, a2={0,0,0,0};
#pragma unroll
      for(int dc=0;dc<11;dc++){
        const bf16x8 kh=*reinterpret_cast<const bf16x8*>(&khi[kb0+(size_t)dc*512]);
        const bf16x8 kl=*reinterpret_cast<const bf16x8*>(&klo[kb0+(size_t)dc*512]);
        a0=__builtin_amdgcn_mfma_f32_16x16x32_bf16(qh[dc],kh,a0,0,0,0);
        a1=__builtin_amdgcn_mfma_f32_16x16x32_bf16(ql[dc],kh,a1,0,0,0);
        a2=__builtin_amdgcn_mfma_f32_16x16x32_bf16(qh[dc],kl,a2,0,0,0);
      }
      const float al=(tt==0)?al0:al1;
      const int tg=t0+tt*16+lm;
#pragma unroll
      for(int r=0;r<4;r++){
        const int srow=quad*4+r;
        const float qk=a0[r]+a1[r]+a2[r];
        const float e=fminf(al-Mr[r],0.f);
        const float msk=(tg<=ws0+srow)?1.f:0.f;
        Sc[w][srow][tt*16+lm]=(short)f2bf(msk*(qk*scale*expf(e)));
      }
    }
    const bf16x8 scf=*reinterpret_cast<const bf16x8*>(&Sc[w][lm][quad*8]);
    const size_t vb0=(((size_t)head*64+c)*22)*512+(size_t)l*8;
#pragma unroll
    for(int nt=0;nt<22;nt++){
      const bf16x8 vf=*reinterpret_cast<const bf16x8*>(&vTf[vb0+(size_t)nt*512]);
      accO[nt]=__builtin_amdgcn_mfma_f32_16x16x32_bf16(scf,vf,accO[nt],0,0,0);
    }
  }

  // ---- cross-parity combine (block-internal, no atomics) ----
  if(par==1){
#pragma unroll
    for(int nt=0;nt<22;nt++)
#pragma unroll
      for(int r=0;r<4;r++) comb[rw][l][nt*4+r]=accO[nt][r];
  }
  __syncthreads();
  if(par==1) return;
#pragma unroll
  for(int nt=0;nt<22;nt++)
#pragma unroll
    for(int r=0;r<4;r++) accO[nt][r]+=comb[rw][l][nt*4+r];

  // ---- fused normalizer + per-head groupnorm + hout store ----
  const int bI=head>>2, nh=head&3;
#pragma unroll
  for(int r=0;r<4;r++){
    float rsv=__shfl(accO[21][r], l&48);    // rowsum lives at lm==0 of nt=21
    float s1=0.f,s2=0.f;
#pragma unroll
    for(int nt=0;nt<21;nt++){ const float v=accO[nt][r]; s1+=v; s2+=v*v; }
#pragma unroll
    for(int m=1;m<16;m<<=1){ s1+=__shfl_xor(s1,m); s2+=__shfl_xor(s2,m); }
    const int srow=quad*4+r;
    const float mt=mtb[hb+ws0+srow];
    const float nn=fmaxf(fabsf(rsv), expf(fminf(fmaxf(-mt,-60.f),60.f)));
    const float inv=1.f/(nn+1e-6f);
    const float mu=s1*inv/336.f;
    const float var=s2*inv*inv/336.f-mu*mu;
    const float rs=rsqrtf(fmaxf(var,0.f)+1e-5f);
    float* orow=hout+((size_t)(bI*S_+ws0+srow))*H_+nh*DH_;
#pragma unroll
    for(int nt=0;nt<21;nt++){
      const int col=nt*16+lm;
      orow[col]=(accO[nt][r]*inv-mu)*rs*lnw[nh*DH_+col];
    }
  }
}

// ---- h_state = (h_out + skip*act) * silu(z) ----
__global__ __launch_bounds__(256) void hstate_k(const float* __restrict__ hout,
                                                const float* __restrict__ act,
                                                const float* __restrict__ xin,
                                                const float* __restrict__ skip,
                                                float* __restrict__ hs){
  const int i=blockIdx.x*256+threadIdx.x;
  if(i>=(int)N_BSH) return;
  const int bs=i/H_, h=i-bs*H_;
  const float z=xin[(size_t)bs*H2_+H_+h];
  hs[(size_t)bs*H_+h]=(hout[(size_t)bs*H_+h]+skip[h]*act[(size_t)bs*H_+h])*siluf(z);
}

// ============================================================================
extern "C" void kernel_launch(void* const* d_in, const int* in_sizes, int n_in,
                              void* d_out, int out_size, void* d_ws, size_t ws_size,
                              hipStream_t stream){
  float* ws=(float*)d_ws;
  int* flag=(int*)ws;

  float* igb  = ws+O_IGB;
  float* logfb= ws+O_LOGF;
  float* ab   = ws+O_AB;
  float* Mbuf = ws+O_MB;
  float* mtb  = ws+O_MTB;
  float* f_ck = ws+O_CK;
  float* f_cb = ws+O_CB;
  float* f_wq = ws+O_WQ;
  float* f_wk = ws+O_WK;
  float* f_wv = ws+O_WV;
  float* f_wig= ws+O_WIG;
  float* f_big= ws+O_BIG;
  float* f_wfg= ws+O_WFG;
  float* f_bfg= ws+O_BFG;
  float* f_lnw= ws+O_LNW;
  float* f_skp= ws+O_SKP;
  float* xin  = ws+O_XIN;
  float* act  = ws+O_ACT;
  float* qb   = ws+O_QB;
  float* kb   = ws+O_KB;
  float* vb   = ws+O_VB;
  float* hout = ws+O_HOUT;
  float* hs   = qb;                            // alias: q dead after mlstm2_k

  unsigned short* xhi  =(unsigned short*)(ws+O_FX);   unsigned short* xlo  =xhi+N_X;
  unsigned short* wuphi=(unsigned short*)(ws+O_FWUP); unsigned short* wuplo=wuphi+N_WUP;
  unsigned short* wdnhi=(unsigned short*)(ws+O_FWDN); unsigned short* wdnlo=wdnhi+N_WDN;
  unsigned short* khi=(unsigned short*)(ws+O_FX);     // x/wup frags dead after up-gemm
  unsigned short* klo=khi+KSPLIT_SHORTS;
  unsigned short* vTf=(unsigned short*)kb;     // kb dead after gates+kprep
  unsigned short* hshi=(unsigned short*)kb;    // vTf dead after mlstm2_k
  unsigned short* hslo=hshi+N_BSH;

  detect_k<<<1,256,0,stream>>>((const unsigned short*)d_in[0],flag);
  auto cvt=[&](int idx,float* dst,size_t n){
    convert_k<<<(int)((n+255)/256),256,0,stream>>>(d_in[idx],dst,(int)n,flag);
  };
  cvt(2,f_ck,N_CK);  cvt(3,f_cb,H_);
  cvt(4,f_wq,N_WH); cvt(5,f_wk,N_WH);   cvt(6,f_wv,N_WH);  cvt(7,f_wig,N_WG);
  cvt(8,f_big,4);   cvt(9,f_wfg,N_WG);  cvt(10,f_bfg,4);   cvt(11,f_lnw,H_);
  cvt(12,f_skp,H_);

  // up-GEMM: xin = x @ Wup  (M=4096,K=1024 kcn=32, N=2688)
  aprep_k<<<(256*32*64+255)/256,256,0,stream>>>(d_in[0],flag,32,1024,256*32*64,xhi,xlo);
  bprep_k<<<(168*32*64+255)/256,256,0,stream>>>(d_in[1],flag,32,2688,168*32*64,wuphi,wuplo);
  gemm_mfma_k<<<dim3(2688/64,4096/128),256,0,stream>>>(xhi,xlo,wuphi,wuplo,xin,nullptr,32,H2_);

  conv_act_k<<<(int)((N_BSH+255)/256),256,0,stream>>>(xin,f_ck,f_cb,act);
  qkv_k<<<(int)((N_BSH+255)/256),256,0,stream>>>(act,xin,f_wq,f_wk,f_wv,qb,kb,vb);
  gates_k<<<(BS_*NH_*8+255)/256,256,0,stream>>>(qb,kb,vb,f_wig,f_big,f_wfg,f_bfg,igb,logfb);
  kprep_k<<<8*128,256,0,stream>>>(kb,khi,klo);
  vprep_k<<<8*64,256,0,stream>>>(vb,vTf);
  // wdn frags (independent; region untouched by khi/klo)
  bprep_k<<<(64*42*64+255)/256,256,0,stream>>>(d_in[13],flag,42,1024,64*42*64,wdnhi,wdnlo);
  scan_k<<<B_*NH_,256,0,stream>>>(igb,logfb,ab,Mbuf,mtb);
  // mLSTM: 512 blocks = 8 heads x 64 row-tiles, no atomics, fused groupnorm
  mlstm2_k<<<512,256,0,stream>>>(qb,khi,klo,vTf,ab,Mbuf,mtb,f_lnw,hout);
  hstate_k<<<(int)((N_BSH+255)/256),256,0,stream>>>(hout,act,xin,f_skp,hs);
  // down-GEMM: out = hs @ Wdn  (M=4096,K=1344 kcn=42, N=1024), direct to d_out
  aprep_k<<<(256*42*64+255)/256,256,0,stream>>>(hs,nullptr,42,1344,256*42*64,hshi,hslo);
  gemm_mfma_k<<<dim3(1024/64,4096/128),256,0,stream>>>(hshi,hslo,wdnhi,wdnlo,d_out,flag,42,E_);
}

// Round 2
// 824.575 us; speedup vs baseline: 1.0781x; 1.0781x over previous
//
#include <hip/hip_runtime.h>
#include <cmath>

#define DI __device__ __forceinline__

constexpr int B_=2, S_=2048, E_=1024, H_=1344, NH_=4, DH_=336;
constexpr int BS_=B_*S_, H2_=2*H_;
constexpr int NG_=B_*NH_*S_;   // 16384

constexpr size_t N_X=(size_t)BS_*E_;
constexpr size_t N_WUP=(size_t)E_*H2_;
constexpr size_t N_WDN=(size_t)H_*E_;
constexpr size_t N_BSH=(size_t)BS_*H_;
constexpr size_t N_BSH2=(size_t)BS_*H2_;
constexpr size_t N_WH=5376, N_WG=16128, N_CK=4*H_;

// ---- ws layout (floats); identical to prior passing rounds ----
constexpr size_t O_IGB = 64;
constexpr size_t O_LOGF= O_IGB + NG_;
constexpr size_t O_AB  = O_LOGF+ NG_;
constexpr size_t O_MB  = O_AB  + NG_;
constexpr size_t O_MTB = O_MB  + NG_;
constexpr size_t O_CK  = O_MTB + NG_;
constexpr size_t O_CB  = O_CK  + N_CK;
constexpr size_t O_WQ  = O_CB  + H_;
constexpr size_t O_WK  = O_WQ  + N_WH;
constexpr size_t O_WV  = O_WK  + N_WH;
constexpr size_t O_WIG = O_WV  + N_WH;
constexpr size_t O_BIG = O_WIG + N_WG;
constexpr size_t O_WFG = O_BIG + 16;
constexpr size_t O_BFG = O_WFG + N_WG;
constexpr size_t O_LNW = O_BFG + 16;
constexpr size_t O_SKP = O_LNW + H_;
constexpr size_t O_FX  = O_SKP + H_;
constexpr size_t O_FWUP= O_FX  + N_X;
constexpr size_t O_FWDN= O_FWUP+ N_WUP;
constexpr size_t O_XIN = O_FWDN+ N_WDN;
constexpr size_t O_ACT = O_XIN + N_BSH2;
constexpr size_t O_QB  = O_ACT + N_BSH;
constexpr size_t O_KB  = O_QB  + N_BSH;
constexpr size_t O_VB  = O_KB  + N_BSH;
constexpr size_t O_HOUT= O_VB  + N_BSH;

// khi/klo: [head][tile=t/16][dc=0..10][l][8] bf16 (B-frag 16x16x32)
constexpr size_t KSPLIT_SHORTS=(size_t)8*128*11*64*8;  // 5,767,168
// vTf: [head][tc=t/32][ntg=0..21][l][8] bf16; n==336 -> 1.0 (rowsum), n>336 -> 0
constexpr size_t VT_SHORTS=(size_t)8*64*22*64*8;       // 5,767,168

typedef __attribute__((ext_vector_type(8))) short bf16x8;
typedef __attribute__((ext_vector_type(4))) float f32x4;

DI float bf2f(unsigned int u){union{unsigned int i;float f;}v;v.i=(u&0xffffu)<<16;return v.f;}
DI unsigned short f2bf(float f){union{float f;unsigned int i;}v;v.f=f;unsigned int x=v.i;
  return (unsigned short)((x+0x7fffu+((x>>16)&1u))>>16);}
DI float siluf(float x){return x/(1.f+expf(-x));}
DI float logsigf(float x){return (x>=0.f)?-log1pf(expf(-x)):x-log1pf(expf(x));}
DI void load4(const float* p, float* d){float4 v=*reinterpret_cast<const float4*>(p);
  d[0]=v.x;d[1]=v.y;d[2]=v.z;d[3]=v.w;}

// ---- dtype detect (fp32 proven; keep the guard) ----
__global__ __launch_bounds__(256) void detect_k(const unsigned short* __restrict__ xraw,
                                                int* __restrict__ flag){
  __shared__ int cnt_s;
  if(threadIdx.x==0) cnt_s=0;
  __syncthreads();
  int c=0;
  for(int i=threadIdx.x;i<2048;i+=256){
    const unsigned e=(xraw[i]>>7)&0xFFu;
    if(e>=0x90u) c++;
  }
  atomicAdd(&cnt_s,c);
  __syncthreads();
  if(threadIdx.x==0) *flag=(cnt_s>16)?0:1;
}

__global__ __launch_bounds__(256) void convert_k(const void* __restrict__ src,
                                                 float* __restrict__ dst,int n,
                                                 const int* __restrict__ flag){
  const int i=blockIdx.x*256+threadIdx.x;
  if(i>=n) return;
  if(*flag) dst[i]=bf2f(((const unsigned short*)src)[i]);
  else      dst[i]=((const float*)src)[i];
}

// ============================================================================
// A-fragment prep
// ============================================================================
__global__ __launch_bounds__(256) void aprep_k(const void* __restrict__ src,
                                               const int* __restrict__ flag,
                                               int kcn,int ldk,int total,
                                               unsigned short* __restrict__ hi,
                                               unsigned short* __restrict__ lo){
  const int slot=blockIdx.x*256+threadIdx.x;
  if(slot>=total) return;
  const int l=slot&63, rest=slot>>6;
  const int kc=rest%kcn, mt=rest/kcn;
  const int row=mt*16+(l&15), k0=kc*32+(l>>4)*8;
  const int fl=flag?*flag:0;
  float v[8];
  if(fl){
    const unsigned short* s=(const unsigned short*)src+(size_t)row*ldk+k0;
    const uint4 u=*reinterpret_cast<const uint4*>(s);
    v[0]=bf2f(u.x);v[1]=bf2f(u.x>>16);v[2]=bf2f(u.y);v[3]=bf2f(u.y>>16);
    v[4]=bf2f(u.z);v[5]=bf2f(u.z>>16);v[6]=bf2f(u.w);v[7]=bf2f(u.w>>16);
  }else{
    const float* s=(const float*)src+(size_t)row*ldk+k0;
    load4(s,v); load4(s+4,v+4);
  }
  unsigned short h8[8], l8[8];
#pragma unroll
  for(int j=0;j<8;j++){ h8[j]=f2bf(v[j]); l8[j]=f2bf(v[j]-bf2f(h8[j])); }
  uint4 ph,pl;
  ph.x=(unsigned)h8[0]|((unsigned)h8[1]<<16); ph.y=(unsigned)h8[2]|((unsigned)h8[3]<<16);
  ph.z=(unsigned)h8[4]|((unsigned)h8[5]<<16); ph.w=(unsigned)h8[6]|((unsigned)h8[7]<<16);
  pl.x=(unsigned)l8[0]|((unsigned)l8[1]<<16); pl.y=(unsigned)l8[2]|((unsigned)l8[3]<<16);
  pl.z=(unsigned)l8[4]|((unsigned)l8[5]<<16); pl.w=(unsigned)l8[6]|((unsigned)l8[7]<<16);
  *reinterpret_cast<uint4*>(&hi[(size_t)slot*8])=ph;
  *reinterpret_cast<uint4*>(&lo[(size_t)slot*8])=pl;
}

// ============================================================================
// B-fragment prep
// ============================================================================
__global__ __launch_bounds__(256) void bprep_k(const void* __restrict__ src,
                                               const int* __restrict__ flag,
                                               int kcn,int ldn,int total,
                                               unsigned short* __restrict__ hi,
                                               unsigned short* __restrict__ lo){
  const int slot=blockIdx.x*256+threadIdx.x;
  if(slot>=total) return;
  const int l=slot&63, rest=slot>>6;
  const int kc=rest%kcn, nt=rest/kcn;
  const int col=nt*16+(l&15), row0=kc*32+(l>>4)*8;
  const int fl=flag?*flag:0;
  float v[8];
  if(fl){
    const unsigned short* s=(const unsigned short*)src;
#pragma unroll
    for(int j=0;j<8;j++) v[j]=bf2f(s[(size_t)(row0+j)*ldn+col]);
  }else{
    const float* s=(const float*)src;
#pragma unroll
    for(int j=0;j<8;j++) v[j]=s[(size_t)(row0+j)*ldn+col];
  }
  unsigned short h8[8], l8[8];
#pragma unroll
  for(int j=0;j<8;j++){ h8[j]=f2bf(v[j]); l8[j]=f2bf(v[j]-bf2f(h8[j])); }
  uint4 ph,pl;
  ph.x=(unsigned)h8[0]|((unsigned)h8[1]<<16); ph.y=(unsigned)h8[2]|((unsigned)h8[3]<<16);
  ph.z=(unsigned)h8[4]|((unsigned)h8[5]<<16); ph.w=(unsigned)h8[6]|((unsigned)h8[7]<<16);
  pl.x=(unsigned)l8[0]|((unsigned)l8[1]<<16); pl.y=(unsigned)l8[2]|((unsigned)l8[3]<<16);
  pl.z=(unsigned)l8[4]|((unsigned)l8[5]<<16); pl.w=(unsigned)l8[6]|((unsigned)l8[7]<<16);
  *reinterpret_cast<uint4*>(&hi[(size_t)slot*8])=ph;
  *reinterpret_cast<uint4*>(&lo[(size_t)slot*8])=pl;
}

// ============================================================================
// MFMA GEMM: 128x64 tile, split-bf16 3-chain, fp32 acc
// ============================================================================
__global__ __launch_bounds__(256) void gemm_mfma_k(
    const unsigned short* __restrict__ Ahi, const unsigned short* __restrict__ Alo,
    const unsigned short* __restrict__ Bhi, const unsigned short* __restrict__ Blo,
    void* __restrict__ C, const int* __restrict__ flag, int kcn, int ldc){
  const int t=threadIdx.x, w=t>>6, l=t&63, lm=l&15, quad=l>>4;
  const int bn=blockIdx.x*64, bm=blockIdx.y*128;
  const int mt0=(bm>>4)+w, mt1=mt0+4;
  const size_t a0=((size_t)mt0*kcn)*512+(size_t)l*8;
  const size_t a1=((size_t)mt1*kcn)*512+(size_t)l*8;
  const size_t b0=((size_t)(bn>>4)*kcn)*512+(size_t)l*8;
  f32x4 acc[2][4];
#pragma unroll
  for(int g=0;g<2;g++)
#pragma unroll
    for(int nt=0;nt<4;nt++) acc[g][nt]={0.f,0.f,0.f,0.f};
  for(int kc=0;kc<kcn;kc++){
    const bf16x8 ah0=*reinterpret_cast<const bf16x8*>(&Ahi[a0+(size_t)kc*512]);
    const bf16x8 al0=*reinterpret_cast<const bf16x8*>(&Alo[a0+(size_t)kc*512]);
    const bf16x8 ah1=*reinterpret_cast<const bf16x8*>(&Ahi[a1+(size_t)kc*512]);
    const bf16x8 al1=*reinterpret_cast<const bf16x8*>(&Alo[a1+(size_t)kc*512]);
#pragma unroll
    for(int nt=0;nt<4;nt++){
      const size_t bo=b0+((size_t)nt*kcn+kc)*512;
      const bf16x8 bh=*reinterpret_cast<const bf16x8*>(&Bhi[bo]);
      const bf16x8 bl=*reinterpret_cast<const bf16x8*>(&Blo[bo]);
      acc[0][nt]=__builtin_amdgcn_mfma_f32_16x16x32_bf16(ah0,bh,acc[0][nt],0,0,0);
      acc[0][nt]=__builtin_amdgcn_mfma_f32_16x16x32_bf16(al0,bh,acc[0][nt],0,0,0);
      acc[0][nt]=__builtin_amdgcn_mfma_f32_16x16x32_bf16(ah0,bl,acc[0][nt],0,0,0);
      acc[1][nt]=__builtin_amdgcn_mfma_f32_16x16x32_bf16(ah1,bh,acc[1][nt],0,0,0);
      acc[1][nt]=__builtin_amdgcn_mfma_f32_16x16x32_bf16(al1,bh,acc[1][nt],0,0,0);
      acc[1][nt]=__builtin_amdgcn_mfma_f32_16x16x32_bf16(ah1,bl,acc[1][nt],0,0,0);
    }
  }
  const int bf=flag?*flag:0;
#pragma unroll
  for(int g=0;g<2;g++)
#pragma unroll
    for(int nt=0;nt<4;nt++)
#pragma unroll
      for(int r=0;r<4;r++){
        const size_t idx=(size_t)(bm+g*64+w*16+quad*4+r)*ldc+bn+nt*16+lm;
        if(bf) ((unsigned short*)C)[idx]=f2bf(acc[g][nt][r]);
        else   ((float*)C)[idx]=acc[g][nt][r];
      }
}

// ---- causal depthwise conv(K=4)+bias -> SiLU ----
__global__ __launch_bounds__(256) void conv_act_k(const float* __restrict__ xin,
                                                  const float* __restrict__ ck,
                                                  const float* __restrict__ cb,
                                                  float* __restrict__ act){
  const int i=blockIdx.x*256+threadIdx.x;
  if(i>=(int)N_BSH) return;
  const int bs=i/H_, h=i-bs*H_;
  const int b=bs/S_, s=bs-b*S_;
  float xc=cb[h];
#pragma unroll
  for(int w=0;w<4;w++){
    const int sr=s-3+w;
    if(sr>=0) xc+=xin[(size_t)(b*S_+sr)*H2_+h]*ck[w*H_+h];
  }
  act[(size_t)bs*H_+h]=siluf(xc);
}

// ---- headwise q/k/v ----
__global__ __launch_bounds__(256) void qkv_k(const float* __restrict__ act,
                                             const float* __restrict__ xin,
                                             const float* __restrict__ Wq,
                                             const float* __restrict__ Wk,
                                             const float* __restrict__ Wv,
                                             float* __restrict__ qb,float* __restrict__ kb,
                                             float* __restrict__ vb){
  const int i=blockIdx.x*256+threadIdx.x;
  if(i>=(int)N_BSH) return;
  const int bs=i/H_, h=i-bs*H_;
  const int b=bs/S_, s=bs-b*S_;
  const int ph=h>>2, o=h&3, base=ph*4;
  float q=0.f,k=0.f,v=0.f;
#pragma unroll
  for(int d=0;d<4;d++){
    const float a=act[(size_t)bs*H_+base+d];
    const float x=xin[(size_t)bs*H2_+base+d];
    q+=a*Wq[ph*16+d*4+o];
    k+=a*Wk[ph*16+d*4+o];
    v+=x*Wv[ph*16+d*4+o];
  }
  const int nh=h/DH_, dh=h-nh*DH_;
  const size_t off=((size_t)(b*NH_+nh)*S_+s)*DH_+dh;
  qb[off]=q; kb[off]=k; vb[off]=v;
}

// ---- gate pre-activations: 8 lanes per output + shfl reduce ----
__global__ __launch_bounds__(256) void gates_k(const float* __restrict__ qb,
                                               const float* __restrict__ kb,
                                               const float* __restrict__ vb,
                                               const float* __restrict__ Wig,
                                               const float* __restrict__ big,
                                               const float* __restrict__ Wfg,
                                               const float* __restrict__ bfg,
                                               float* __restrict__ igb,float* __restrict__ logfb){
  const int i=blockIdx.x*256+threadIdx.x;
  if(i>=BS_*NH_*8) return;
  const int sub=i&7, out=i>>3;
  const int n=out&3, bs=out>>2;
  const int b=bs/S_, s=bs-b*S_;
  const int d0=sub*42;                       // 336/8 = 42 contiguous per lane
  float sig=0.f,sfg=0.f;
  for(int nh=0;nh<NH_;nh++){
    const size_t rb=((size_t)(b*NH_+nh)*S_+s)*DH_;
    for(int dh=d0;dh<d0+42;dh++){
      const int h=nh*DH_+dh;
      const float q=qb[rb+dh], k=kb[rb+dh], v=vb[rb+dh];
      sig+=q*Wig[h*4+n]+k*Wig[(H_+h)*4+n]+v*Wig[(2*H_+h)*4+n];
      sfg+=q*Wfg[h*4+n]+k*Wfg[(H_+h)*4+n]+v*Wfg[(2*H_+h)*4+n];
    }
  }
#pragma unroll
  for(int m=1;m<8;m<<=1){ sig+=__shfl_xor(sig,m); sfg+=__shfl_xor(sfg,m); }
  if(sub==0){
    const size_t off=(size_t)(b*NH_+n)*S_+s;
    igb[off]=sig+big[n];
    logfb[off]=logsigf(sfg+bfg[n]);
  }
}

// ---- K prep: split fp32 K into hi/lo bf16, MFMA B-fragment tile layout ----
__global__ __launch_bounds__(256) void kprep_k(const float* __restrict__ kb,
                                               unsigned short* __restrict__ khi,
                                               unsigned short* __restrict__ klo){
  const int blk=blockIdx.x;                 // 8 heads * 128 t-tiles
  const int head=blk>>7, tt=blk&127;
  const size_t obase=(size_t)blk*11*512;
  for(int slot=threadIdx.x; slot<704; slot+=256){
    const int dc=slot>>6, ll=slot&63, quad=ll>>4, lm=ll&15;
    const int tg=tt*16+lm, dbase=dc*32+quad*8;
    float v[8];
    if(dbase<336){
      load4(&kb[((size_t)head*S_+tg)*DH_+dbase],v);
      load4(&kb[((size_t)head*S_+tg)*DH_+dbase+4],v+4);
    } else { for(int j=0;j<8;j++) v[j]=0.f; }
    unsigned short hi8[8], lo8[8];
#pragma unroll
    for(int j=0;j<8;j++){
      hi8[j]=f2bf(v[j]);
      lo8[j]=f2bf(v[j]-bf2f(hi8[j]));
    }
    const size_t o=obase+(size_t)(dc*64+ll)*8;
    uint4 ph, pl;
    ph.x=(unsigned)hi8[0]|((unsigned)hi8[1]<<16); ph.y=(unsigned)hi8[2]|((unsigned)hi8[3]<<16);
    ph.z=(unsigned)hi8[4]|((unsigned)hi8[5]<<16); ph.w=(unsigned)hi8[6]|((unsigned)hi8[7]<<16);
    pl.x=(unsigned)lo8[0]|((unsigned)lo8[1]<<16); pl.y=(unsigned)lo8[2]|((unsigned)lo8[3]<<16);
    pl.z=(unsigned)lo8[4]|((unsigned)lo8[5]<<16); pl.w=(unsigned)lo8[6]|((unsigned)lo8[7]<<16);
    *reinterpret_cast<uint4*>(&khi[o])=ph;
    *reinterpret_cast<uint4*>(&klo[o])=pl;
  }
}

// ---- V prep: V^T bf16 in MFMA B-fragment tile layout; col 336 = ones ----
__global__ __launch_bounds__(256) void vprep_k(const float* __restrict__ vb,
                                               unsigned short* __restrict__ vTf){
  const int blk=blockIdx.x;                 // 8 heads * 64 t-chunks
  const int head=blk>>6, tc=blk&63;
  const size_t obase=(size_t)blk*22*512;
  for(int slot=threadIdx.x; slot<1408; slot+=256){
    const int ntg=slot>>6, ll=slot&63, quad=ll>>4, lm=ll&15;
    const int n=ntg*16+lm, t0=tc*32+quad*8;
    unsigned short h8[8];
#pragma unroll
    for(int j=0;j<8;j++){
      float val;
      if(n<336)       val=vb[((size_t)head*S_+t0+j)*DH_+n];
      else if(n==336) val=1.f;
      else            val=0.f;
      h8[j]=f2bf(val);
    }
    uint4 pk;
    pk.x=(unsigned)h8[0]|((unsigned)h8[1]<<16); pk.y=(unsigned)h8[2]|((unsigned)h8[3]<<16);
    pk.z=(unsigned)h8[4]|((unsigned)h8[5]<<16); pk.w=(unsigned)h8[6]|((unsigned)h8[7]<<16);
    *reinterpret_cast<uint4*>(&vTf[obase+(size_t)(ntg*64+ll)*8])=pk;
  }
}

// ---- parallel per-head scan ----
__global__ __launch_bounds__(256) void scan_k(const float* __restrict__ igb,
                                              const float* __restrict__ logfb,
                                              float* __restrict__ ab,float* __restrict__ Mb,
                                              float* __restrict__ mtb){
  const int head=blockIdx.x, t=threadIdx.x;
  __shared__ float sh[256];
  const float* lf=logfb+(size_t)head*S_;
  const float* ig=igb+(size_t)head*S_;
  float lc[8];
  float run=0.f;
#pragma unroll
  for(int i=0;i<8;i++){ run+=lf[t*8+i]; lc[i]=run; }
  sh[t]=run;
  for(int st=1;st<256;st<<=1){
    __syncthreads();
    const float v=(t>=st)?sh[t-st]:0.f;
    __syncthreads();
    sh[t]+=v;
  }
  __syncthreads();
  const float off=(t==0)?0.f:sh[t-1];
  __syncthreads();
  float av[8],mv[8],cv[8];
  float mrun=-1e30f;
#pragma unroll
  for(int i=0;i<8;i++){
    cv[i]=off+lc[i];
    av[i]=ig[t*8+i]-cv[i];
    mrun=fmaxf(mrun,av[i]);
    mv[i]=mrun;
  }
  sh[t]=mrun;
  for(int st=1;st<256;st<<=1){
    __syncthreads();
    const float v=(t>=st)?sh[t-st]:-1e30f;
    __syncthreads();
    sh[t]=fmaxf(sh[t],v);
  }
  __syncthreads();
  const float moff=(t==0)?-1e30f:sh[t-1];
#pragma unroll
  for(int i=0;i<8;i++){
    const float Mi=fmaxf(moff,mv[i]);
    const size_t j=(size_t)head*S_+t*8+i;
    ab[j]=av[i]; Mb[j]=Mi; mtb[j]=cv[i]+Mi;
  }
}

// ============================================================================
// mLSTM v8 — paired 64-row supertiles, LDS-staged K/V double buffer.
// Block = (head, pair p<->31-p, seg 0/1): 256 blocks, 33 chunks each (uniform).
// 4 row-waves consume the SAME staged chunk (4x VMEM cut vs per-wave loads).
// T14 pipeline: issue next chunk's global loads early, ds_write late, 1 barrier
// per chunk. Breaks the register-pressure latency serialization of v6/v7.
// Output: v6-style atomic part/rsum + separate finalize.
// ============================================================================
__global__ __launch_bounds__(256,1) void mlstm3_k(
    const float* __restrict__ qb, const unsigned short* __restrict__ khi,
    const unsigned short* __restrict__ klo, const unsigned short* __restrict__ vTf,
    const float* __restrict__ ab, const float* __restrict__ Mb,
    float* __restrict__ part, float* __restrict__ rsum){
  const int bid=blockIdx.x;
  const int head=bid&7;                     // XCD pin: head h -> XCD h
  const int rest=bid>>3;                    // 0..31
  const int pairI=rest>>1, seg=rest&1;
  const int t=threadIdx.x, w=t>>6, l=t&63, lm=l&15, quad=l>>4;

  // LDS: double-buffered chunk staging (66 frag-tiles of 512 shorts each)
  // layout per buffer: [0..21]=khi(2tt x 11dc), [22..43]=klo, [44..65]=vTf
  __shared__ short KV[2][66*512];
  __shared__ short Sc[4][16][40];

  const size_t hb=(size_t)head*S_;
  const float scale=0.05455447256f;         // 336^-0.5

  const int sbA=pairI, sbB=31-pairI;
  const int nA=sbA+1, nTot=33;              // uniform work across all blocks

  bf16x8 qh[11], ql[11];
  f32x4 accO[22];
  float Mr[4];
  int ws0=sbA*64+w*16;

  auto loadQ=[&](int ws0_){
    const float* qrow=qb+(hb+ws0_+lm)*DH_;
#pragma unroll
    for(int dc=0;dc<11;dc++){
      const int dbase=dc*32+quad*8;
      float v[8];
      if(dbase<336){ load4(qrow+dbase,v); load4(qrow+dbase+4,v+4); }
      else { for(int j=0;j<8;j++) v[j]=0.f; }
#pragma unroll
      for(int j=0;j<8;j++){
        const unsigned short h=f2bf(v[j]);
        qh[dc][j]=(short)h;
        ql[dc][j]=(short)f2bf(v[j]-bf2f(h));
      }
    }
#pragma unroll
    for(int r=0;r<4;r++) Mr[r]=Mb[hb+ws0_+quad*4+r];
#pragma unroll
    for(int n=0;n<22;n++) accO[n]={0.f,0.f,0.f,0.f};
  };

  // item i -> chunk index c (32-col chunks)
  auto itemC=[&](int i)->int{
    return (i<nA)? (seg+2*i) : (seg+2*(i-nA));
  };

  uint4 stg[17];                            // staging regs (wave w: tr=w+4j)
  auto stageLoad=[&](int c){
    const size_t kbase=(((size_t)head*128+(size_t)(2*c))*11)*512+(size_t)l*8;
    const size_t vbase=(((size_t)head*64+(size_t)c)*22)*512+(size_t)l*8;
#pragma unroll
    for(int j=0;j<17;j++){
      const int tr=w+4*j;
      if(tr<66){
        const unsigned short* src;
        if(tr<22)      src=&khi[kbase+(size_t)tr*512];
        else if(tr<44) src=&klo[kbase+(size_t)(tr-22)*512];
        else           src=&vTf[vbase+(size_t)(tr-44)*512];
        stg[j]=*reinterpret_cast<const uint4*>(src);
      }
    }
  };
  auto stageWrite=[&](int buf){
#pragma unroll
    for(int j=0;j<17;j++){
      const int tr=w+4*j;
      if(tr<66)
        *reinterpret_cast<uint4*>(&KV[buf][(size_t)tr*512+(size_t)l*8])=stg[j];
    }
  };

  auto compute=[&](int c,int buf){
    const int t0=c<<5;
    const float al0=ab[hb+t0+lm];
    const float al1=ab[hb+t0+16+lm];
#pragma unroll
    for(int tt=0;tt<2;tt++){
      f32x4 a0={0,0,0,0}, a1={0,0,0,0}, a2={0,0,0,0};
#pragma unroll
      for(int dc=0;dc<11;dc++){
        const bf16x8 kh=*reinterpret_cast<const bf16x8*>(&KV[buf][(tt*11+dc)*512+l*8]);
        const bf16x8 kl=*reinterpret_cast<const bf16x8*>(&KV[buf][(22+tt*11+dc)*512+l*8]);
        a0=__builtin_amdgcn_mfma_f32_16x16x32_bf16(qh[dc],kh,a0,0,0,0);
        a1=__builtin_amdgcn_mfma_f32_16x16x32_bf16(ql[dc],kh,a1,0,0,0);
        a2=__builtin_amdgcn_mfma_f32_16x16x32_bf16(qh[dc],kl,a2,0,0,0);
      }
      const float al=(tt==0)?al0:al1;
      const int tg=t0+tt*16+lm;
#pragma unroll
      for(int r=0;r<4;r++){
        const int srow=quad*4+r;
        const float qk=a0[r]+a1[r]+a2[r];
        const float e=fminf(al-Mr[r],0.f);
        const float msk=(tg<=ws0+srow)?1.f:0.f;
        Sc[w][srow][tt*16+lm]=(short)f2bf(msk*(qk*scale*expf(e)));
      }
    }
    const bf16x8 scf=*reinterpret_cast<const bf16x8*>(&Sc[w][lm][quad*8]);
#pragma unroll
    for(int nt=0;nt<22;nt++){
      const bf16x8 vf=*reinterpret_cast<const bf16x8*>(&KV[buf][(44+nt)*512+l*8]);
      accO[nt]=__builtin_amdgcn_mfma_f32_16x16x32_bf16(scf,vf,accO[nt],0,0,0);
    }
  };

  auto epilogue=[&](){
    const size_t pbase=(size_t)head*2048+ws0;
#pragma unroll
    for(int nt=0;nt<22;nt++){
      const int col=nt*16+lm;
#pragma unroll
      for(int r=0;r<4;r++){
        const int srow=quad*4+r;
        const float val=accO[nt][r];
        if(col<336){ if(val!=0.f) atomicAdd(&part[(pbase+srow)*336+col],val); }
        else if(col==336){ if(val!=0.f) atomicAdd(&rsum[pbase+srow],val); }
      }
    }
  };

  loadQ(ws0);
  stageLoad(itemC(0));
  stageWrite(0);
  __syncthreads();
  int cur=0;
  for(int i=0;i<nTot;i++){
    if(i+1<nTot) stageLoad(itemC(i+1));     // issue-early (hides under compute)
    compute(itemC(i),cur);
    if(i==nA-1){                            // tile switch: A done
      epilogue();
      ws0=sbB*64+w*16;
      loadQ(ws0);
    }
    if(i+1<nTot) stageWrite(cur^1);         // write-late into other buffer
    __syncthreads();
    cur^=1;
  }
  epilogue();                               // tile B
}

// ============================================================================
// finalize: n-normalizer + per-head groupnorm + hout write (v6, proven).
// ============================================================================
__global__ __launch_bounds__(256) void finalize_k(const float* __restrict__ part,
                                                  const float* __restrict__ rsum,
                                                  const float* __restrict__ mtb,
                                                  const float* __restrict__ lnw,
                                                  float* __restrict__ hout){
  const int sblk=blockIdx.x, head=blockIdx.y;
  const int bI=head>>2, nh=head&3;
  const int s0=sblk*32;
  const int t=threadIdx.x, row=t>>3, sub=t&7;
  __shared__ float red1[32][8], red2[32][8];
  __shared__ float mu_s[32], rs_s[32], inv_s[32];
  const size_t pbase=(size_t)head*2048+s0;
  const float* prow=part+(pbase+row)*336;
  float s1=0.f,s2=0.f;
  for(int c=sub;c<336;c+=8){ const float v=prow[c]; s1+=v; s2+=v*v; }
  red1[row][sub]=s1; red2[row][sub]=s2;
  __syncthreads();
  if(sub==0){
    float a1=0.f,a2=0.f;
#pragma unroll
    for(int j=0;j<8;j++){ a1+=red1[row][j]; a2+=red2[row][j]; }
    const float mt=mtb[(size_t)head*S_+s0+row];
    const float nn=fmaxf(fabsf(rsum[pbase+row]), expf(fminf(fmaxf(-mt,-60.f),60.f)));
    const float inv=1.f/(nn+1e-6f);
    const float mu=a1*inv/336.f;
    const float var=a2*inv*inv/336.f-mu*mu;
    inv_s[row]=inv; mu_s[row]=mu;
    rs_s[row]=rsqrtf(fmaxf(var,0.f)+1e-5f);
  }
  __syncthreads();
  const float inv=inv_s[row], mu=mu_s[row], rs=rs_s[row];
  float* orow=hout+((size_t)(bI*S_+s0+row))*H_+nh*DH_;
  for(int c=sub;c<336;c+=8)
    orow[c]=(prow[c]*inv-mu)*rs*lnw[nh*DH_+c];
}

// ---- h_state = (h_out + skip*act) * silu(z) ----
__global__ __launch_bounds__(256) void hstate_k(const float* __restrict__ hout,
                                                const float* __restrict__ act,
                                                const float* __restrict__ xin,
                                                const float* __restrict__ skip,
                                                float* __restrict__ hs){
  const int i=blockIdx.x*256+threadIdx.x;
  if(i>=(int)N_BSH) return;
  const int bs=i/H_, h=i-bs*H_;
  const float z=xin[(size_t)bs*H2_+H_+h];
  hs[(size_t)bs*H_+h]=(hout[(size_t)bs*H_+h]+skip[h]*act[(size_t)bs*H_+h])*siluf(z);
}

// ============================================================================
extern "C" void kernel_launch(void* const* d_in, const int* in_sizes, int n_in,
                              void* d_out, int out_size, void* d_ws, size_t ws_size,
                              hipStream_t stream){
  float* ws=(float*)d_ws;
  int* flag=(int*)ws;

  float* igb  = ws+O_IGB;
  float* logfb= ws+O_LOGF;
  float* ab   = ws+O_AB;
  float* Mbuf = ws+O_MB;
  float* mtb  = ws+O_MTB;
  float* f_ck = ws+O_CK;
  float* f_cb = ws+O_CB;
  float* f_wq = ws+O_WQ;
  float* f_wk = ws+O_WK;
  float* f_wv = ws+O_WV;
  float* f_wig= ws+O_WIG;
  float* f_big= ws+O_BIG;
  float* f_wfg= ws+O_WFG;
  float* f_bfg= ws+O_BFG;
  float* f_lnw= ws+O_LNW;
  float* f_skp= ws+O_SKP;
  float* xin  = ws+O_XIN;
  float* act  = ws+O_ACT;
  float* qb   = ws+O_QB;
  float* kb   = ws+O_KB;
  float* vb   = ws+O_VB;
  float* hout = ws+O_HOUT;
  float* hs   = qb;                            // alias: q dead after mlstm3_k

  unsigned short* xhi  =(unsigned short*)(ws+O_FX);   unsigned short* xlo  =xhi+N_X;
  unsigned short* wuphi=(unsigned short*)(ws+O_FWUP); unsigned short* wuplo=wuphi+N_WUP;
  unsigned short* wdnhi=(unsigned short*)(ws+O_FWDN); unsigned short* wdnlo=wdnhi+N_WDN;
  unsigned short* khi=(unsigned short*)(ws+O_FX);     // x/wup frags dead after up-gemm
  unsigned short* klo=khi+KSPLIT_SHORTS;
  unsigned short* vTf=(unsigned short*)kb;     // kb dead after gates+kprep
  unsigned short* hshi=(unsigned short*)kb;    // vTf dead after mlstm3_k
  unsigned short* hslo=hshi+N_BSH;
  float* partb=vb;                             // vb dead after vprep
  float* rsumb=igb;                            // igb dead after scan_k

  detect_k<<<1,256,0,stream>>>((const unsigned short*)d_in[0],flag);
  auto cvt=[&](int idx,float* dst,size_t n){
    convert_k<<<(int)((n+255)/256),256,0,stream>>>(d_in[idx],dst,(int)n,flag);
  };
  cvt(2,f_ck,N_CK);  cvt(3,f_cb,H_);
  cvt(4,f_wq,N_WH); cvt(5,f_wk,N_WH);   cvt(6,f_wv,N_WH);  cvt(7,f_wig,N_WG);
  cvt(8,f_big,4);   cvt(9,f_wfg,N_WG);  cvt(10,f_bfg,4);   cvt(11,f_lnw,H_);
  cvt(12,f_skp,H_);

  // up-GEMM: xin = x @ Wup  (M=4096,K=1024 kcn=32, N=2688)
  aprep_k<<<(256*32*64+255)/256,256,0,stream>>>(d_in[0],flag,32,1024,256*32*64,xhi,xlo);
  bprep_k<<<(168*32*64+255)/256,256,0,stream>>>(d_in[1],flag,32,2688,168*32*64,wuphi,wuplo);
  gemm_mfma_k<<<dim3(2688/64,4096/128),256,0,stream>>>(xhi,xlo,wuphi,wuplo,xin,nullptr,32,H2_);

  conv_act_k<<<(int)((N_BSH+255)/256),256,0,stream>>>(xin,f_ck,f_cb,act);
  qkv_k<<<(int)((N_BSH+255)/256),256,0,stream>>>(act,xin,f_wq,f_wk,f_wv,qb,kb,vb);
  gates_k<<<(BS_*NH_*8+255)/256,256,0,stream>>>(qb,kb,vb,f_wig,f_big,f_wfg,f_bfg,igb,logfb);
  kprep_k<<<8*128,256,0,stream>>>(kb,khi,klo);
  vprep_k<<<8*64,256,0,stream>>>(vb,vTf);
  // wdn frags (independent; region untouched by khi/klo)
  bprep_k<<<(64*42*64+255)/256,256,0,stream>>>(d_in[13],flag,42,1024,64*42*64,wdnhi,wdnlo);
  scan_k<<<B_*NH_,256,0,stream>>>(igb,logfb,ab,Mbuf,mtb);
  hipMemsetAsync(partb,0,N_BSH*sizeof(float),stream);
  hipMemsetAsync(rsumb,0,(size_t)NG_*sizeof(float),stream);
  // mLSTM v8: 256 blocks = 8 heads x 16 pairs x 2 seg; 33 chunks/block uniform
  mlstm3_k<<<256,256,0,stream>>>(qb,khi,klo,vTf,ab,Mbuf,partb,rsumb);
  finalize_k<<<dim3(S_/32,B_*NH_),256,0,stream>>>(partb,rsumb,mtb,f_lnw,hout);
  hstate_k<<<(int)((N_BSH+255)/256),256,0,stream>>>(hout,act,xin,f_skp,hs);
  // down-GEMM: out = hs @ Wdn  (M=4096,K=1344 kcn=42, N=1024), direct to d_out
  aprep_k<<<(256*42*64+255)/256,256,0,stream>>>(hs,nullptr,42,1344,256*42*64,hshi,hslo);
  gemm_mfma_k<<<dim3(1024/64,4096/128),256,0,stream>>>(hshi,hslo,wdnhi,wdnlo,d_out,flag,42,E_);
}

// Round 3
// 639.745 us; speedup vs baseline: 1.3895x; 1.2889x over previous
//
#include <hip/hip_runtime.h>
#include <cmath>

#define DI __device__ __forceinline__

constexpr int B_=2, S_=2048, E_=1024, H_=1344, NH_=4, DH_=336;
constexpr int BS_=B_*S_, H2_=2*H_;
constexpr int NG_=B_*NH_*S_;   // 16384

constexpr size_t N_X=(size_t)BS_*E_;
constexpr size_t N_WUP=(size_t)E_*H2_;
constexpr size_t N_WDN=(size_t)H_*E_;
constexpr size_t N_BSH=(size_t)BS_*H_;
constexpr size_t N_BSH2=(size_t)BS_*H2_;
constexpr size_t N_WH=5376, N_WG=16128, N_CK=4*H_;

// ---- ws layout (floats); identical to prior passing rounds ----
constexpr size_t O_IGB = 64;
constexpr size_t O_LOGF= O_IGB + NG_;
constexpr size_t O_AB  = O_LOGF+ NG_;
constexpr size_t O_MB  = O_AB  + NG_;
constexpr size_t O_MTB = O_MB  + NG_;
constexpr size_t O_CK  = O_MTB + NG_;
constexpr size_t O_CB  = O_CK  + N_CK;
constexpr size_t O_WQ  = O_CB  + H_;
constexpr size_t O_WK  = O_WQ  + N_WH;
constexpr size_t O_WV  = O_WK  + N_WH;
constexpr size_t O_WIG = O_WV  + N_WH;
constexpr size_t O_BIG = O_WIG + N_WG;
constexpr size_t O_WFG = O_BIG + 16;
constexpr size_t O_BFG = O_WFG + N_WG;
constexpr size_t O_LNW = O_BFG + 16;
constexpr size_t O_SKP = O_LNW + H_;
constexpr size_t O_FX  = O_SKP + H_;
constexpr size_t O_FWUP= O_FX  + N_X;
constexpr size_t O_FWDN= O_FWUP+ N_WUP;
constexpr size_t O_XIN = O_FWDN+ N_WDN;
constexpr size_t O_ACT = O_XIN + N_BSH2;
constexpr size_t O_QB  = O_ACT + N_BSH;
constexpr size_t O_KB  = O_QB  + N_BSH;
constexpr size_t O_VB  = O_KB  + N_BSH;
constexpr size_t O_HOUT= O_VB  + N_BSH;

// khi/klo: [head][tile=t/16][dc=0..10][l][8] bf16 (B-frag 16x16x32)
constexpr size_t KSPLIT_SHORTS=(size_t)8*128*11*64*8;  // 5,767,168
// vTf: [head][tc=t/32][ntg=0..21][l][8] bf16; n==336 -> 1.0 (rowsum), n>336 -> 0
constexpr size_t VT_SHORTS=(size_t)8*64*22*64*8;       // 5,767,168

typedef __attribute__((ext_vector_type(8))) short bf16x8;
typedef __attribute__((ext_vector_type(4))) float f32x4;

DI float bf2f(unsigned int u){union{unsigned int i;float f;}v;v.i=(u&0xffffu)<<16;return v.f;}
DI unsigned short f2bf(float f){union{float f;unsigned int i;}v;v.f=f;unsigned int x=v.i;
  return (unsigned short)((x+0x7fffu+((x>>16)&1u))>>16);}
DI float siluf(float x){return x/(1.f+expf(-x));}
DI float logsigf(float x){return (x>=0.f)?-log1pf(expf(-x)):x-log1pf(expf(x));}
DI void load4(const float* p, float* d){float4 v=*reinterpret_cast<const float4*>(p);
  d[0]=v.x;d[1]=v.y;d[2]=v.z;d[3]=v.w;}

// ---- dtype detect (fp32 proven; keep the guard) ----
__global__ __launch_bounds__(256) void detect_k(const unsigned short* __restrict__ xraw,
                                                int* __restrict__ flag){
  __shared__ int cnt_s;
  if(threadIdx.x==0) cnt_s=0;
  __syncthreads();
  int c=0;
  for(int i=threadIdx.x;i<2048;i+=256){
    const unsigned e=(xraw[i]>>7)&0xFFu;
    if(e>=0x90u) c++;
  }
  atomicAdd(&cnt_s,c);
  __syncthreads();
  if(threadIdx.x==0) *flag=(cnt_s>16)?0:1;
}

__global__ __launch_bounds__(256) void convert_k(const void* __restrict__ src,
                                                 float* __restrict__ dst,int n,
                                                 const int* __restrict__ flag){
  const int i=blockIdx.x*256+threadIdx.x;
  if(i>=n) return;
  if(*flag) dst[i]=bf2f(((const unsigned short*)src)[i]);
  else      dst[i]=((const float*)src)[i];
}

// ============================================================================
// A-fragment prep
// ============================================================================
__global__ __launch_bounds__(256) void aprep_k(const void* __restrict__ src,
                                               const int* __restrict__ flag,
                                               int kcn,int ldk,int total,
                                               unsigned short* __restrict__ hi,
                                               unsigned short* __restrict__ lo){
  const int slot=blockIdx.x*256+threadIdx.x;
  if(slot>=total) return;
  const int l=slot&63, rest=slot>>6;
  const int kc=rest%kcn, mt=rest/kcn;
  const int row=mt*16+(l&15), k0=kc*32+(l>>4)*8;
  const int fl=flag?*flag:0;
  float v[8];
  if(fl){
    const unsigned short* s=(const unsigned short*)src+(size_t)row*ldk+k0;
    const uint4 u=*reinterpret_cast<const uint4*>(s);
    v[0]=bf2f(u.x);v[1]=bf2f(u.x>>16);v[2]=bf2f(u.y);v[3]=bf2f(u.y>>16);
    v[4]=bf2f(u.z);v[5]=bf2f(u.z>>16);v[6]=bf2f(u.w);v[7]=bf2f(u.w>>16);
  }else{
    const float* s=(const float*)src+(size_t)row*ldk+k0;
    load4(s,v); load4(s+4,v+4);
  }
  unsigned short h8[8], l8[8];
#pragma unroll
  for(int j=0;j<8;j++){ h8[j]=f2bf(v[j]); l8[j]=f2bf(v[j]-bf2f(h8[j])); }
  uint4 ph,pl;
  ph.x=(unsigned)h8[0]|((unsigned)h8[1]<<16); ph.y=(unsigned)h8[2]|((unsigned)h8[3]<<16);
  ph.z=(unsigned)h8[4]|((unsigned)h8[5]<<16); ph.w=(unsigned)h8[6]|((unsigned)h8[7]<<16);
  pl.x=(unsigned)l8[0]|((unsigned)l8[1]<<16); pl.y=(unsigned)l8[2]|((unsigned)l8[3]<<16);
  pl.z=(unsigned)l8[4]|((unsigned)l8[5]<<16); pl.w=(unsigned)l8[6]|((unsigned)l8[7]<<16);
  *reinterpret_cast<uint4*>(&hi[(size_t)slot*8])=ph;
  *reinterpret_cast<uint4*>(&lo[(size_t)slot*8])=pl;
}

// ============================================================================
// B-fragment prep
// ============================================================================
__global__ __launch_bounds__(256) void bprep_k(const void* __restrict__ src,
                                               const int* __restrict__ flag,
                                               int kcn,int ldn,int total,
                                               unsigned short* __restrict__ hi,
                                               unsigned short* __restrict__ lo){
  const int slot=blockIdx.x*256+threadIdx.x;
  if(slot>=total) return;
  const int l=slot&63, rest=slot>>6;
  const int kc=rest%kcn, nt=rest/kcn;
  const int col=nt*16+(l&15), row0=kc*32+(l>>4)*8;
  const int fl=flag?*flag:0;
  float v[8];
  if(fl){
    const unsigned short* s=(const unsigned short*)src;
#pragma unroll
    for(int j=0;j<8;j++) v[j]=bf2f(s[(size_t)(row0+j)*ldn+col]);
  }else{
    const float* s=(const float*)src;
#pragma unroll
    for(int j=0;j<8;j++) v[j]=s[(size_t)(row0+j)*ldn+col];
  }
  unsigned short h8[8], l8[8];
#pragma unroll
  for(int j=0;j<8;j++){ h8[j]=f2bf(v[j]); l8[j]=f2bf(v[j]-bf2f(h8[j])); }
  uint4 ph,pl;
  ph.x=(unsigned)h8[0]|((unsigned)h8[1]<<16); ph.y=(unsigned)h8[2]|((unsigned)h8[3]<<16);
  ph.z=(unsigned)h8[4]|((unsigned)h8[5]<<16); ph.w=(unsigned)h8[6]|((unsigned)h8[7]<<16);
  pl.x=(unsigned)l8[0]|((unsigned)l8[1]<<16); pl.y=(unsigned)l8[2]|((unsigned)l8[3]<<16);
  pl.z=(unsigned)l8[4]|((unsigned)l8[5]<<16); pl.w=(unsigned)l8[6]|((unsigned)l8[7]<<16);
  *reinterpret_cast<uint4*>(&hi[(size_t)slot*8])=ph;
  *reinterpret_cast<uint4*>(&lo[(size_t)slot*8])=pl;
}

// ============================================================================
// MFMA GEMM: 128x64 tile, split-bf16 3-chain, fp32 acc
// ============================================================================
__global__ __launch_bounds__(256) void gemm_mfma_k(
    const unsigned short* __restrict__ Ahi, const unsigned short* __restrict__ Alo,
    const unsigned short* __restrict__ Bhi, const unsigned short* __restrict__ Blo,
    void* __restrict__ C, const int* __restrict__ flag, int kcn, int ldc){
  const int t=threadIdx.x, w=t>>6, l=t&63, lm=l&15, quad=l>>4;
  const int bn=blockIdx.x*64, bm=blockIdx.y*128;
  const int mt0=(bm>>4)+w, mt1=mt0+4;
  const size_t a0=((size_t)mt0*kcn)*512+(size_t)l*8;
  const size_t a1=((size_t)mt1*kcn)*512+(size_t)l*8;
  const size_t b0=((size_t)(bn>>4)*kcn)*512+(size_t)l*8;
  f32x4 acc[2][4];
#pragma unroll
  for(int g=0;g<2;g++)
#pragma unroll
    for(int nt=0;nt<4;nt++) acc[g][nt]={0.f,0.f,0.f,0.f};
  for(int kc=0;kc<kcn;kc++){
    const bf16x8 ah0=*reinterpret_cast<const bf16x8*>(&Ahi[a0+(size_t)kc*512]);
    const bf16x8 al0=*reinterpret_cast<const bf16x8*>(&Alo[a0+(size_t)kc*512]);
    const bf16x8 ah1=*reinterpret_cast<const bf16x8*>(&Ahi[a1+(size_t)kc*512]);
    const bf16x8 al1=*reinterpret_cast<const bf16x8*>(&Alo[a1+(size_t)kc*512]);
#pragma unroll
    for(int nt=0;nt<4;nt++){
      const size_t bo=b0+((size_t)nt*kcn+kc)*512;
      const bf16x8 bh=*reinterpret_cast<const bf16x8*>(&Bhi[bo]);
      const bf16x8 bl=*reinterpret_cast<const bf16x8*>(&Blo[bo]);
      acc[0][nt]=__builtin_amdgcn_mfma_f32_16x16x32_bf16(ah0,bh,acc[0][nt],0,0,0);
      acc[0][nt]=__builtin_amdgcn_mfma_f32_16x16x32_bf16(al0,bh,acc[0][nt],0,0,0);
      acc[0][nt]=__builtin_amdgcn_mfma_f32_16x16x32_bf16(ah0,bl,acc[0][nt],0,0,0);
      acc[1][nt]=__builtin_amdgcn_mfma_f32_16x16x32_bf16(ah1,bh,acc[1][nt],0,0,0);
      acc[1][nt]=__builtin_amdgcn_mfma_f32_16x16x32_bf16(al1,bh,acc[1][nt],0,0,0);
      acc[1][nt]=__builtin_amdgcn_mfma_f32_16x16x32_bf16(ah1,bl,acc[1][nt],0,0,0);
    }
  }
  const int bf=flag?*flag:0;
#pragma unroll
  for(int g=0;g<2;g++)
#pragma unroll
    for(int nt=0;nt<4;nt++)
#pragma unroll
      for(int r=0;r<4;r++){
        const size_t idx=(size_t)(bm+g*64+w*16+quad*4+r)*ldc+bn+nt*16+lm;
        if(bf) ((unsigned short*)C)[idx]=f2bf(acc[g][nt][r]);
        else   ((float*)C)[idx]=acc[g][nt][r];
      }
}

// ---- causal depthwise conv(K=4)+bias -> SiLU ----
__global__ __launch_bounds__(256) void conv_act_k(const float* __restrict__ xin,
                                                  const float* __restrict__ ck,
                                                  const float* __restrict__ cb,
                                                  float* __restrict__ act){
  const int i=blockIdx.x*256+threadIdx.x;
  if(i>=(int)N_BSH) return;
  const int bs=i/H_, h=i-bs*H_;
  const int b=bs/S_, s=bs-b*S_;
  float xc=cb[h];
#pragma unroll
  for(int w=0;w<4;w++){
    const int sr=s-3+w;
    if(sr>=0) xc+=xin[(size_t)(b*S_+sr)*H2_+h]*ck[w*H_+h];
  }
  act[(size_t)bs*H_+h]=siluf(xc);
}

// ---- headwise q/k/v ----
__global__ __launch_bounds__(256) void qkv_k(const float* __restrict__ act,
                                             const float* __restrict__ xin,
                                             const float* __restrict__ Wq,
                                             const float* __restrict__ Wk,
                                             const float* __restrict__ Wv,
                                             float* __restrict__ qb,float* __restrict__ kb,
                                             float* __restrict__ vb){
  const int i=blockIdx.x*256+threadIdx.x;
  if(i>=(int)N_BSH) return;
  const int bs=i/H_, h=i-bs*H_;
  const int b=bs/S_, s=bs-b*S_;
  const int ph=h>>2, o=h&3, base=ph*4;
  float q=0.f,k=0.f,v=0.f;
#pragma unroll
  for(int d=0;d<4;d++){
    const float a=act[(size_t)bs*H_+base+d];
    const float x=xin[(size_t)bs*H2_+base+d];
    q+=a*Wq[ph*16+d*4+o];
    k+=a*Wk[ph*16+d*4+o];
    v+=x*Wv[ph*16+d*4+o];
  }
  const int nh=h/DH_, dh=h-nh*DH_;
  const size_t off=((size_t)(b*NH_+nh)*S_+s)*DH_+dh;
  qb[off]=q; kb[off]=k; vb[off]=v;
}

// ---- gate pre-activations: 8 lanes per output + shfl reduce ----
__global__ __launch_bounds__(256) void gates_k(const float* __restrict__ qb,
                                               const float* __restrict__ kb,
                                               const float* __restrict__ vb,
                                               const float* __restrict__ Wig,
                                               const float* __restrict__ big,
                                               const float* __restrict__ Wfg,
                                               const float* __restrict__ bfg,
                                               float* __restrict__ igb,float* __restrict__ logfb){
  const int i=blockIdx.x*256+threadIdx.x;
  if(i>=BS_*NH_*8) return;
  const int sub=i&7, out=i>>3;
  const int n=out&3, bs=out>>2;
  const int b=bs/S_, s=bs-b*S_;
  const int d0=sub*42;                       // 336/8 = 42 contiguous per lane
  float sig=0.f,sfg=0.f;
  for(int nh=0;nh<NH_;nh++){
    const size_t rb=((size_t)(b*NH_+nh)*S_+s)*DH_;
    for(int dh=d0;dh<d0+42;dh++){
      const int h=nh*DH_+dh;
      const float q=qb[rb+dh], k=kb[rb+dh], v=vb[rb+dh];
      sig+=q*Wig[h*4+n]+k*Wig[(H_+h)*4+n]+v*Wig[(2*H_+h)*4+n];
      sfg+=q*Wfg[h*4+n]+k*Wfg[(H_+h)*4+n]+v*Wfg[(2*H_+h)*4+n];
    }
  }
#pragma unroll
  for(int m=1;m<8;m<<=1){ sig+=__shfl_xor(sig,m); sfg+=__shfl_xor(sfg,m); }
  if(sub==0){
    const size_t off=(size_t)(b*NH_+n)*S_+s;
    igb[off]=sig+big[n];
    logfb[off]=logsigf(sfg+bfg[n]);
  }
}

// ---- K prep: split fp32 K into hi/lo bf16, MFMA B-fragment tile layout ----
__global__ __launch_bounds__(256) void kprep_k(const float* __restrict__ kb,
                                               unsigned short* __restrict__ khi,
                                               unsigned short* __restrict__ klo){
  const int blk=blockIdx.x;                 // 8 heads * 128 t-tiles
  const int head=blk>>7, tt=blk&127;
  const size_t obase=(size_t)blk*11*512;
  for(int slot=threadIdx.x; slot<704; slot+=256){
    const int dc=slot>>6, ll=slot&63, quad=ll>>4, lm=ll&15;
    const int tg=tt*16+lm, dbase=dc*32+quad*8;
    float v[8];
    if(dbase<336){
      load4(&kb[((size_t)head*S_+tg)*DH_+dbase],v);
      load4(&kb[((size_t)head*S_+tg)*DH_+dbase+4],v+4);
    } else { for(int j=0;j<8;j++) v[j]=0.f; }
    unsigned short hi8[8], lo8[8];
#pragma unroll
    for(int j=0;j<8;j++){
      hi8[j]=f2bf(v[j]);
      lo8[j]=f2bf(v[j]-bf2f(hi8[j]));
    }
    const size_t o=obase+(size_t)(dc*64+ll)*8;
    uint4 ph, pl;
    ph.x=(unsigned)hi8[0]|((unsigned)hi8[1]<<16); ph.y=(unsigned)hi8[2]|((unsigned)hi8[3]<<16);
    ph.z=(unsigned)hi8[4]|((unsigned)hi8[5]<<16); ph.w=(unsigned)hi8[6]|((unsigned)hi8[7]<<16);
    pl.x=(unsigned)lo8[0]|((unsigned)lo8[1]<<16); pl.y=(unsigned)lo8[2]|((unsigned)lo8[3]<<16);
    pl.z=(unsigned)lo8[4]|((unsigned)lo8[5]<<16); pl.w=(unsigned)lo8[6]|((unsigned)lo8[7]<<16);
    *reinterpret_cast<uint4*>(&khi[o])=ph;
    *reinterpret_cast<uint4*>(&klo[o])=pl;
  }
}

// ---- V prep: V^T bf16 in MFMA B-fragment tile layout; col 336 = ones ----
__global__ __launch_bounds__(256) void vprep_k(const float* __restrict__ vb,
                                               unsigned short* __restrict__ vTf){
  const int blk=blockIdx.x;                 // 8 heads * 64 t-chunks
  const int head=blk>>6, tc=blk&63;
  const size_t obase=(size_t)blk*22*512;
  for(int slot=threadIdx.x; slot<1408; slot+=256){
    const int ntg=slot>>6, ll=slot&63, quad=ll>>4, lm=ll&15;
    const int n=ntg*16+lm, t0=tc*32+quad*8;
    unsigned short h8[8];
#pragma unroll
    for(int j=0;j<8;j++){
      float val;
      if(n<336)       val=vb[((size_t)head*S_+t0+j)*DH_+n];
      else if(n==336) val=1.f;
      else            val=0.f;
      h8[j]=f2bf(val);
    }
    uint4 pk;
    pk.x=(unsigned)h8[0]|((unsigned)h8[1]<<16); pk.y=(unsigned)h8[2]|((unsigned)h8[3]<<16);
    pk.z=(unsigned)h8[4]|((unsigned)h8[5]<<16); pk.w=(unsigned)h8[6]|((unsigned)h8[7]<<16);
    *reinterpret_cast<uint4*>(&vTf[obase+(size_t)(ntg*64+ll)*8])=pk;
  }
}

// ---- parallel per-head scan ----
__global__ __launch_bounds__(256) void scan_k(const float* __restrict__ igb,
                                              const float* __restrict__ logfb,
                                              float* __restrict__ ab,float* __restrict__ Mb,
                                              float* __restrict__ mtb){
  const int head=blockIdx.x, t=threadIdx.x;
  __shared__ float sh[256];
  const float* lf=logfb+(size_t)head*S_;
  const float* ig=igb+(size_t)head*S_;
  float lc[8];
  float run=0.f;
#pragma unroll
  for(int i=0;i<8;i++){ run+=lf[t*8+i]; lc[i]=run; }
  sh[t]=run;
  for(int st=1;st<256;st<<=1){
    __syncthreads();
    const float v=(t>=st)?sh[t-st]:0.f;
    __syncthreads();
    sh[t]+=v;
  }
  __syncthreads();
  const float off=(t==0)?0.f:sh[t-1];
  __syncthreads();
  float av[8],mv[8],cv[8];
  float mrun=-1e30f;
#pragma unroll
  for(int i=0;i<8;i++){
    cv[i]=off+lc[i];
    av[i]=ig[t*8+i]-cv[i];
    mrun=fmaxf(mrun,av[i]);
    mv[i]=mrun;
  }
  sh[t]=mrun;
  for(int st=1;st<256;st<<=1){
    __syncthreads();
    const float v=(t>=st)?sh[t-st]:-1e30f;
    __syncthreads();
    sh[t]=fmaxf(sh[t],v);
  }
  __syncthreads();
  const float moff=(t==0)?-1e30f:sh[t-1];
#pragma unroll
  for(int i=0;i<8;i++){
    const float Mi=fmaxf(moff,mv[i]);
    const size_t j=(size_t)head*S_+t*8+i;
    ab[j]=av[i]; Mb[j]=Mi; mtb[j]=cv[i]+Mi;
  }
}

// ============================================================================
// mLSTM v9 — paired supertiles + global_load_lds DMA staging (no VGPR
// round-trip, no spills). Block = (head, pair p<->31-p, seg): 256 blocks,
// 33 chunks each. Double-buffered LDS; one __syncthreads per chunk drains
// vmcnt (loads had the whole compute phase to land).
// ============================================================================
__global__ __launch_bounds__(256,1) void mlstm4_k(
    const float* __restrict__ qb, const unsigned short* __restrict__ khi,
    const unsigned short* __restrict__ klo, const unsigned short* __restrict__ vTf,
    const float* __restrict__ ab, const float* __restrict__ Mb,
    float* __restrict__ part, float* __restrict__ rsum){
  const int bid=blockIdx.x;
  const int head=bid&7;                     // XCD pin: head h -> XCD h
  const int rest=bid>>3;                    // 0..31
  const int pairI=rest>>1, seg=rest&1;
  const int t=threadIdx.x, w=t>>6, l=t&63, lm=l&15, quad=l>>4;

  // LDS: double-buffered chunk staging (66 frag-tiles of 512 shorts each)
  // layout per buffer: [0..21]=khi(2tt x 11dc), [22..43]=klo, [44..65]=vTf
  __shared__ short KV[2][66*512];
  __shared__ short Sc[4][16][40];

  const size_t hb=(size_t)head*S_;
  const float scale=0.05455447256f;         // 336^-0.5

  const int sbA=pairI, sbB=31-pairI;
  const int nA=sbA+1, nTot=33;              // uniform work across all blocks

  bf16x8 qh[11], ql[11];
  f32x4 accO[22];
  float Mr[4];
  int ws0=sbA*64+w*16;

  auto loadQ=[&](int ws0_){
    const float* qrow=qb+(hb+ws0_+lm)*DH_;
#pragma unroll
    for(int dc=0;dc<11;dc++){
      const int dbase=dc*32+quad*8;
      float v[8];
      if(dbase<336){ load4(qrow+dbase,v); load4(qrow+dbase+4,v+4); }
      else { for(int j=0;j<8;j++) v[j]=0.f; }
#pragma unroll
      for(int j=0;j<8;j++){
        const unsigned short h=f2bf(v[j]);
        qh[dc][j]=(short)h;
        ql[dc][j]=(short)f2bf(v[j]-bf2f(h));
      }
    }
#pragma unroll
    for(int r=0;r<4;r++) Mr[r]=Mb[hb+ws0_+quad*4+r];
#pragma unroll
    for(int n=0;n<22;n++) accO[n]={0.f,0.f,0.f,0.f};
  };

  // item i -> chunk index c (32-col chunks)
  auto itemC=[&](int i)->int{
    return (i<nA)? (seg+2*i) : (seg+2*(i-nA));
  };

  // direct global->LDS DMA: per frag-tile, 64 lanes x 16B = 1024B.
  // LDS dest is wave-uniform base (+lane*16 implicit); global src is per-lane.
  auto stage=[&](int buf,int c){
    const size_t kbase=(((size_t)head*128+(size_t)(2*c))*11)*512+(size_t)l*8;
    const size_t vbase=(((size_t)head*64+(size_t)c)*22)*512+(size_t)l*8;
#pragma unroll
    for(int j=0;j<17;j++){
      const int tr=w+4*j;
      if(tr<66){
        const unsigned short* src;
        if(tr<22)      src=&khi[kbase+(size_t)tr*512];
        else if(tr<44) src=&klo[kbase+(size_t)(tr-22)*512];
        else           src=&vTf[vbase+(size_t)(tr-44)*512];
        __builtin_amdgcn_global_load_lds(
          (const __attribute__((address_space(1))) unsigned int*)src,
          (__attribute__((address_space(3))) unsigned int*)&KV[buf][(size_t)tr*512],
          16,0,0);
      }
    }
  };

  auto compute=[&](int c,int buf){
    const int t0=c<<5;
    const float al0=ab[hb+t0+lm];
    const float al1=ab[hb+t0+16+lm];
#pragma unroll
    for(int tt=0;tt<2;tt++){
      f32x4 a0={0,0,0,0}, a1={0,0,0,0}, a2={0,0,0,0};
#pragma unroll
      for(int dc=0;dc<11;dc++){
        const bf16x8 kh=*reinterpret_cast<const bf16x8*>(&KV[buf][(tt*11+dc)*512+l*8]);
        const bf16x8 kl=*reinterpret_cast<const bf16x8*>(&KV[buf][(22+tt*11+dc)*512+l*8]);
        a0=__builtin_amdgcn_mfma_f32_16x16x32_bf16(qh[dc],kh,a0,0,0,0);
        a1=__builtin_amdgcn_mfma_f32_16x16x32_bf16(ql[dc],kh,a1,0,0,0);
        a2=__builtin_amdgcn_mfma_f32_16x16x32_bf16(qh[dc],kl,a2,0,0,0);
      }
      const float al=(tt==0)?al0:al1;
      const int tg=t0+tt*16+lm;
#pragma unroll
      for(int r=0;r<4;r++){
        const int srow=quad*4+r;
        const float qk=a0[r]+a1[r]+a2[r];
        const float e=fminf(al-Mr[r],0.f);
        const float msk=(tg<=ws0+srow)?1.f:0.f;
        Sc[w][srow][tt*16+lm]=(short)f2bf(msk*(qk*scale*expf(e)));
      }
    }
    const bf16x8 scf=*reinterpret_cast<const bf16x8*>(&Sc[w][lm][quad*8]);
#pragma unroll
    for(int nt=0;nt<22;nt++){
      const bf16x8 vf=*reinterpret_cast<const bf16x8*>(&KV[buf][(44+nt)*512+l*8]);
      accO[nt]=__builtin_amdgcn_mfma_f32_16x16x32_bf16(scf,vf,accO[nt],0,0,0);
    }
  };

  auto epilogue=[&](){
    const size_t pbase=(size_t)head*2048+ws0;
#pragma unroll
    for(int nt=0;nt<22;nt++){
      const int col=nt*16+lm;
#pragma unroll
      for(int r=0;r<4;r++){
        const int srow=quad*4+r;
        const float val=accO[nt][r];
        if(col<336){ if(val!=0.f) atomicAdd(&part[(pbase+srow)*336+col],val); }
        else if(col==336){ if(val!=0.f) atomicAdd(&rsum[pbase+srow],val); }
      }
    }
  };

  loadQ(ws0);
  stage(0,itemC(0));
  __syncthreads();                          // drains vmcnt: buffer 0 ready
  int cur=0;
  for(int i=0;i<nTot;i++){
    if(i+1<nTot) stage(cur^1,itemC(i+1));   // DMA next chunk into back buffer
    compute(itemC(i),cur);
    if(i==nA-1){                            // tile switch: A done
      epilogue();
      ws0=sbB*64+w*16;
      loadQ(ws0);
    }
    __syncthreads();                        // drain DMA + cross-wave sync
    cur^=1;
  }
  epilogue();                               // tile B
}

// ============================================================================
// finalize: n-normalizer + per-head groupnorm + hout write (v6, proven).
// ============================================================================
__global__ __launch_bounds__(256) void finalize_k(const float* __restrict__ part,
                                                  const float* __restrict__ rsum,
                                                  const float* __restrict__ mtb,
                                                  const float* __restrict__ lnw,
                                                  float* __restrict__ hout){
  const int sblk=blockIdx.x, head=blockIdx.y;
  const int bI=head>>2, nh=head&3;
  const int s0=sblk*32;
  const int t=threadIdx.x, row=t>>3, sub=t&7;
  __shared__ float red1[32][8], red2[32][8];
  __shared__ float mu_s[32], rs_s[32], inv_s[32];
  const size_t pbase=(size_t)head*2048+s0;
  const float* prow=part+(pbase+row)*336;
  float s1=0.f,s2=0.f;
  for(int c=sub;c<336;c+=8){ const float v=prow[c]; s1+=v; s2+=v*v; }
  red1[row][sub]=s1; red2[row][sub]=s2;
  __syncthreads();
  if(sub==0){
    float a1=0.f,a2=0.f;
#pragma unroll
    for(int j=0;j<8;j++){ a1+=red1[row][j]; a2+=red2[row][j]; }
    const float mt=mtb[(size_t)head*S_+s0+row];
    const float nn=fmaxf(fabsf(rsum[pbase+row]), expf(fminf(fmaxf(-mt,-60.f),60.f)));
    const float inv=1.f/(nn+1e-6f);
    const float mu=a1*inv/336.f;
    const float var=a2*inv*inv/336.f-mu*mu;
    inv_s[row]=inv; mu_s[row]=mu;
    rs_s[row]=rsqrtf(fmaxf(var,0.f)+1e-5f);
  }
  __syncthreads();
  const float inv=inv_s[row], mu=mu_s[row], rs=rs_s[row];
  float* orow=hout+((size_t)(bI*S_+s0+row))*H_+nh*DH_;
  for(int c=sub;c<336;c+=8)
    orow[c]=(prow[c]*inv-mu)*rs*lnw[nh*DH_+c];
}

// ---- h_state = (h_out + skip*act) * silu(z) ----
__global__ __launch_bounds__(256) void hstate_k(const float* __restrict__ hout,
                                                const float* __restrict__ act,
                                                const float* __restrict__ xin,
                                                const float* __restrict__ skip,
                                                float* __restrict__ hs){
  const int i=blockIdx.x*256+threadIdx.x;
  if(i>=(int)N_BSH) return;
  const int bs=i/H_, h=i-bs*H_;
  const float z=xin[(size_t)bs*H2_+H_+h];
  hs[(size_t)bs*H_+h]=(hout[(size_t)bs*H_+h]+skip[h]*act[(size_t)bs*H_+h])*siluf(z);
}

// ============================================================================
extern "C" void kernel_launch(void* const* d_in, const int* in_sizes, int n_in,
                              void* d_out, int out_size, void* d_ws, size_t ws_size,
                              hipStream_t stream){
  float* ws=(float*)d_ws;
  int* flag=(int*)ws;

  float* igb  = ws+O_IGB;
  float* logfb= ws+O_LOGF;
  float* ab   = ws+O_AB;
  float* Mbuf = ws+O_MB;
  float* mtb  = ws+O_MTB;
  float* f_ck = ws+O_CK;
  float* f_cb = ws+O_CB;
  float* f_wq = ws+O_WQ;
  float* f_wk = ws+O_WK;
  float* f_wv = ws+O_WV;
  float* f_wig= ws+O_WIG;
  float* f_big= ws+O_BIG;
  float* f_wfg= ws+O_WFG;
  float* f_bfg= ws+O_BFG;
  float* f_lnw= ws+O_LNW;
  float* f_skp= ws+O_SKP;
  float* xin  = ws+O_XIN;
  float* act  = ws+O_ACT;
  float* qb   = ws+O_QB;
  float* kb   = ws+O_KB;
  float* vb   = ws+O_VB;
  float* hout = ws+O_HOUT;
  float* hs   = qb;                            // alias: q dead after mlstm4_k

  unsigned short* xhi  =(unsigned short*)(ws+O_FX);   unsigned short* xlo  =xhi+N_X;
  unsigned short* wuphi=(unsigned short*)(ws+O_FWUP); unsigned short* wuplo=wuphi+N_WUP;
  unsigned short* wdnhi=(unsigned short*)(ws+O_FWDN); unsigned short* wdnlo=wdnhi+N_WDN;
  unsigned short* khi=(unsigned short*)(ws+O_FX);     // x/wup frags dead after up-gemm
  unsigned short* klo=khi+KSPLIT_SHORTS;
  unsigned short* vTf=(unsigned short*)kb;     // kb dead after gates+kprep
  unsigned short* hshi=(unsigned short*)kb;    // vTf dead after mlstm4_k
  unsigned short* hslo=hshi+N_BSH;
  float* partb=vb;                             // vb dead after vprep
  float* rsumb=igb;                            // igb dead after scan_k

  detect_k<<<1,256,0,stream>>>((const unsigned short*)d_in[0],flag);
  auto cvt=[&](int idx,float* dst,size_t n){
    convert_k<<<(int)((n+255)/256),256,0,stream>>>(d_in[idx],dst,(int)n,flag);
  };
  cvt(2,f_ck,N_CK);  cvt(3,f_cb,H_);
  cvt(4,f_wq,N_WH); cvt(5,f_wk,N_WH);   cvt(6,f_wv,N_WH);  cvt(7,f_wig,N_WG);
  cvt(8,f_big,4);   cvt(9,f_wfg,N_WG);  cvt(10,f_bfg,4);   cvt(11,f_lnw,H_);
  cvt(12,f_skp,H_);

  // up-GEMM: xin = x @ Wup  (M=4096,K=1024 kcn=32, N=2688)
  aprep_k<<<(256*32*64+255)/256,256,0,stream>>>(d_in[0],flag,32,1024,256*32*64,xhi,xlo);
  bprep_k<<<(168*32*64+255)/256,256,0,stream>>>(d_in[1],flag,32,2688,168*32*64,wuphi,wuplo);
  gemm_mfma_k<<<dim3(2688/64,4096/128),256,0,stream>>>(xhi,xlo,wuphi,wuplo,xin,nullptr,32,H2_);

  conv_act_k<<<(int)((N_BSH+255)/256),256,0,stream>>>(xin,f_ck,f_cb,act);
  qkv_k<<<(int)((N_BSH+255)/256),256,0,stream>>>(act,xin,f_wq,f_wk,f_wv,qb,kb,vb);
  gates_k<<<(BS_*NH_*8+255)/256,256,0,stream>>>(qb,kb,vb,f_wig,f_big,f_wfg,f_bfg,igb,logfb);
  kprep_k<<<8*128,256,0,stream>>>(kb,khi,klo);
  vprep_k<<<8*64,256,0,stream>>>(vb,vTf);
  // wdn frags (independent; region untouched by khi/klo)
  bprep_k<<<(64*42*64+255)/256,256,0,stream>>>(d_in[13],flag,42,1024,64*42*64,wdnhi,wdnlo);
  scan_k<<<B_*NH_,256,0,stream>>>(igb,logfb,ab,Mbuf,mtb);
  hipMemsetAsync(partb,0,N_BSH*sizeof(float),stream);
  hipMemsetAsync(rsumb,0,(size_t)NG_*sizeof(float),stream);
  // mLSTM v9: 256 blocks = 8 heads x 16 pairs x 2 seg; 33 chunks/block uniform
  mlstm4_k<<<256,256,0,stream>>>(qb,khi,klo,vTf,ab,Mbuf,partb,rsumb);
  finalize_k<<<dim3(S_/32,B_*NH_),256,0,stream>>>(partb,rsumb,mtb,f_lnw,hout);
  hstate_k<<<(int)((N_BSH+255)/256),256,0,stream>>>(hout,act,xin,f_skp,hs);
  // down-GEMM: out = hs @ Wdn  (M=4096,K=1344 kcn=42, N=1024), direct to d_out
  aprep_k<<<(256*42*64+255)/256,256,0,stream>>>(hs,nullptr,42,1344,256*42*64,hshi,hslo);
  gemm_mfma_k<<<dim3(1024/64,4096/128),256,0,stream>>>(hshi,hslo,wdnhi,wdnlo,d_out,flag,42,E_);
}

// Round 4
// 541.570 us; speedup vs baseline: 1.6414x; 1.1813x over previous
//
#include <hip/hip_runtime.h>
#include <cmath>

#define DI __device__ __forceinline__

constexpr int B_=2, S_=2048, E_=1024, H_=1344, NH_=4, DH_=336;
constexpr int BS_=B_*S_, H2_=2*H_;
constexpr int NG_=B_*NH_*S_;   // 16384

constexpr size_t N_X=(size_t)BS_*E_;
constexpr size_t N_WUP=(size_t)E_*H2_;
constexpr size_t N_WDN=(size_t)H_*E_;
constexpr size_t N_BSH=(size_t)BS_*H_;
constexpr size_t N_BSH2=(size_t)BS_*H2_;
constexpr size_t N_WH=5376, N_WG=16128, N_CK=4*H_;

// ---- ws layout (floats); identical to prior passing rounds ----
constexpr size_t O_IGB = 64;
constexpr size_t O_LOGF= O_IGB + NG_;
constexpr size_t O_AB  = O_LOGF+ NG_;
constexpr size_t O_MB  = O_AB  + NG_;
constexpr size_t O_MTB = O_MB  + NG_;
constexpr size_t O_CK  = O_MTB + NG_;
constexpr size_t O_CB  = O_CK  + N_CK;
constexpr size_t O_WQ  = O_CB  + H_;
constexpr size_t O_WK  = O_WQ  + N_WH;
constexpr size_t O_WV  = O_WK  + N_WH;
constexpr size_t O_WIG = O_WV  + N_WH;
constexpr size_t O_BIG = O_WIG + N_WG;
constexpr size_t O_WFG = O_BIG + 16;
constexpr size_t O_BFG = O_WFG + N_WG;
constexpr size_t O_LNW = O_BFG + 16;
constexpr size_t O_SKP = O_LNW + H_;
constexpr size_t O_FX  = O_SKP + H_;
constexpr size_t O_FWUP= O_FX  + N_X;
constexpr size_t O_FWDN= O_FWUP+ N_WUP;
constexpr size_t O_XIN = O_FWDN+ N_WDN;
constexpr size_t O_ACT = O_XIN + N_BSH2;
constexpr size_t O_QB  = O_ACT + N_BSH;
constexpr size_t O_KB  = O_QB  + N_BSH;
constexpr size_t O_VB  = O_KB  + N_BSH;
constexpr size_t O_HOUT= O_VB  + N_BSH;

// khi/klo: [head][tile=t/16][dc=0..10][l][8] bf16 (B-frag 16x16x32)
constexpr size_t KSPLIT_SHORTS=(size_t)8*128*11*64*8;  // 5,767,168
// vTf: [head][tc=t/32][ntg=0..21][l][8] bf16; n==336 -> 1.0 (rowsum), n>336 -> 0
constexpr size_t VT_SHORTS=(size_t)8*64*22*64*8;       // 5,767,168

typedef __attribute__((ext_vector_type(8))) short bf16x8;
typedef __attribute__((ext_vector_type(4))) float f32x4;

DI float bf2f(unsigned int u){union{unsigned int i;float f;}v;v.i=(u&0xffffu)<<16;return v.f;}
DI unsigned short f2bf(float f){union{float f;unsigned int i;}v;v.f=f;unsigned int x=v.i;
  return (unsigned short)((x+0x7fffu+((x>>16)&1u))>>16);}
DI float siluf(float x){return x/(1.f+expf(-x));}
DI float logsigf(float x){return (x>=0.f)?-log1pf(expf(-x)):x-log1pf(expf(x));}
DI void load4(const float* p, float* d){float4 v=*reinterpret_cast<const float4*>(p);
  d[0]=v.x;d[1]=v.y;d[2]=v.z;d[3]=v.w;}

// ---- dtype detect (fp32 proven; keep the guard) ----
__global__ __launch_bounds__(256) void detect_k(const unsigned short* __restrict__ xraw,
                                                int* __restrict__ flag){
  __shared__ int cnt_s;
  if(threadIdx.x==0) cnt_s=0;
  __syncthreads();
  int c=0;
  for(int i=threadIdx.x;i<2048;i+=256){
    const unsigned e=(xraw[i]>>7)&0xFFu;
    if(e>=0x90u) c++;
  }
  atomicAdd(&cnt_s,c);
  __syncthreads();
  if(threadIdx.x==0) *flag=(cnt_s>16)?0:1;
}

__global__ __launch_bounds__(256) void convert_k(const void* __restrict__ src,
                                                 float* __restrict__ dst,int n,
                                                 const int* __restrict__ flag){
  const int i=blockIdx.x*256+threadIdx.x;
  if(i>=n) return;
  if(*flag) dst[i]=bf2f(((const unsigned short*)src)[i]);
  else      dst[i]=((const float*)src)[i];
}

// ============================================================================
// A-fragment prep
// ============================================================================
__global__ __launch_bounds__(256) void aprep_k(const void* __restrict__ src,
                                               const int* __restrict__ flag,
                                               int kcn,int ldk,int total,
                                               unsigned short* __restrict__ hi,
                                               unsigned short* __restrict__ lo){
  const int slot=blockIdx.x*256+threadIdx.x;
  if(slot>=total) return;
  const int l=slot&63, rest=slot>>6;
  const int kc=rest%kcn, mt=rest/kcn;
  const int row=mt*16+(l&15), k0=kc*32+(l>>4)*8;
  const int fl=flag?*flag:0;
  float v[8];
  if(fl){
    const unsigned short* s=(const unsigned short*)src+(size_t)row*ldk+k0;
    const uint4 u=*reinterpret_cast<const uint4*>(s);
    v[0]=bf2f(u.x);v[1]=bf2f(u.x>>16);v[2]=bf2f(u.y);v[3]=bf2f(u.y>>16);
    v[4]=bf2f(u.z);v[5]=bf2f(u.z>>16);v[6]=bf2f(u.w);v[7]=bf2f(u.w>>16);
  }else{
    const float* s=(const float*)src+(size_t)row*ldk+k0;
    load4(s,v); load4(s+4,v+4);
  }
  unsigned short h8[8], l8[8];
#pragma unroll
  for(int j=0;j<8;j++){ h8[j]=f2bf(v[j]); l8[j]=f2bf(v[j]-bf2f(h8[j])); }
  uint4 ph,pl;
  ph.x=(unsigned)h8[0]|((unsigned)h8[1]<<16); ph.y=(unsigned)h8[2]|((unsigned)h8[3]<<16);
  ph.z=(unsigned)h8[4]|((unsigned)h8[5]<<16); ph.w=(unsigned)h8[6]|((unsigned)h8[7]<<16);
  pl.x=(unsigned)l8[0]|((unsigned)l8[1]<<16); pl.y=(unsigned)l8[2]|((unsigned)l8[3]<<16);
  pl.z=(unsigned)l8[4]|((unsigned)l8[5]<<16); pl.w=(unsigned)l8[6]|((unsigned)l8[7]<<16);
  *reinterpret_cast<uint4*>(&hi[(size_t)slot*8])=ph;
  *reinterpret_cast<uint4*>(&lo[(size_t)slot*8])=pl;
}

// ============================================================================
// B-fragment prep
// ============================================================================
__global__ __launch_bounds__(256) void bprep_k(const void* __restrict__ src,
                                               const int* __restrict__ flag,
                                               int kcn,int ldn,int total,
                                               unsigned short* __restrict__ hi,
                                               unsigned short* __restrict__ lo){
  const int slot=blockIdx.x*256+threadIdx.x;
  if(slot>=total) return;
  const int l=slot&63, rest=slot>>6;
  const int kc=rest%kcn, nt=rest/kcn;
  const int col=nt*16+(l&15), row0=kc*32+(l>>4)*8;
  const int fl=flag?*flag:0;
  float v[8];
  if(fl){
    const unsigned short* s=(const unsigned short*)src;
#pragma unroll
    for(int j=0;j<8;j++) v[j]=bf2f(s[(size_t)(row0+j)*ldn+col]);
  }else{
    const float* s=(const float*)src;
#pragma unroll
    for(int j=0;j<8;j++) v[j]=s[(size_t)(row0+j)*ldn+col];
  }
  unsigned short h8[8], l8[8];
#pragma unroll
  for(int j=0;j<8;j++){ h8[j]=f2bf(v[j]); l8[j]=f2bf(v[j]-bf2f(h8[j])); }
  uint4 ph,pl;
  ph.x=(unsigned)h8[0]|((unsigned)h8[1]<<16); ph.y=(unsigned)h8[2]|((unsigned)h8[3]<<16);
  ph.z=(unsigned)h8[4]|((unsigned)h8[5]<<16); ph.w=(unsigned)h8[6]|((unsigned)h8[7]<<16);
  pl.x=(unsigned)l8[0]|((unsigned)l8[1]<<16); pl.y=(unsigned)l8[2]|((unsigned)l8[3]<<16);
  pl.z=(unsigned)l8[4]|((unsigned)l8[5]<<16); pl.w=(unsigned)l8[6]|((unsigned)l8[7]<<16);
  *reinterpret_cast<uint4*>(&hi[(size_t)slot*8])=ph;
  *reinterpret_cast<uint4*>(&lo[(size_t)slot*8])=pl;
}

// ============================================================================
// MFMA GEMM: 128x64 tile, split-bf16 3-chain, fp32 acc
// ============================================================================
__global__ __launch_bounds__(256) void gemm_mfma_k(
    const unsigned short* __restrict__ Ahi, const unsigned short* __restrict__ Alo,
    const unsigned short* __restrict__ Bhi, const unsigned short* __restrict__ Blo,
    void* __restrict__ C, const int* __restrict__ flag, int kcn, int ldc){
  const int t=threadIdx.x, w=t>>6, l=t&63, lm=l&15, quad=l>>4;
  const int bn=blockIdx.x*64, bm=blockIdx.y*128;
  const int mt0=(bm>>4)+w, mt1=mt0+4;
  const size_t a0=((size_t)mt0*kcn)*512+(size_t)l*8;
  const size_t a1=((size_t)mt1*kcn)*512+(size_t)l*8;
  const size_t b0=((size_t)(bn>>4)*kcn)*512+(size_t)l*8;
  f32x4 acc[2][4];
#pragma unroll
  for(int g=0;g<2;g++)
#pragma unroll
    for(int nt=0;nt<4;nt++) acc[g][nt]={0.f,0.f,0.f,0.f};
  for(int kc=0;kc<kcn;kc++){
    const bf16x8 ah0=*reinterpret_cast<const bf16x8*>(&Ahi[a0+(size_t)kc*512]);
    const bf16x8 al0=*reinterpret_cast<const bf16x8*>(&Alo[a0+(size_t)kc*512]);
    const bf16x8 ah1=*reinterpret_cast<const bf16x8*>(&Ahi[a1+(size_t)kc*512]);
    const bf16x8 al1=*reinterpret_cast<const bf16x8*>(&Alo[a1+(size_t)kc*512]);
#pragma unroll
    for(int nt=0;nt<4;nt++){
      const size_t bo=b0+((size_t)nt*kcn+kc)*512;
      const bf16x8 bh=*reinterpret_cast<const bf16x8*>(&Bhi[bo]);
      const bf16x8 bl=*reinterpret_cast<const bf16x8*>(&Blo[bo]);
      acc[0][nt]=__builtin_amdgcn_mfma_f32_16x16x32_bf16(ah0,bh,acc[0][nt],0,0,0);
      acc[0][nt]=__builtin_amdgcn_mfma_f32_16x16x32_bf16(al0,bh,acc[0][nt],0,0,0);
      acc[0][nt]=__builtin_amdgcn_mfma_f32_16x16x32_bf16(ah0,bl,acc[0][nt],0,0,0);
      acc[1][nt]=__builtin_amdgcn_mfma_f32_16x16x32_bf16(ah1,bh,acc[1][nt],0,0,0);
      acc[1][nt]=__builtin_amdgcn_mfma_f32_16x16x32_bf16(al1,bh,acc[1][nt],0,0,0);
      acc[1][nt]=__builtin_amdgcn_mfma_f32_16x16x32_bf16(ah1,bl,acc[1][nt],0,0,0);
    }
  }
  const int bf=flag?*flag:0;
#pragma unroll
  for(int g=0;g<2;g++)
#pragma unroll
    for(int nt=0;nt<4;nt++)
#pragma unroll
      for(int r=0;r<4;r++){
        const size_t idx=(size_t)(bm+g*64+w*16+quad*4+r)*ldc+bn+nt*16+lm;
        if(bf) ((unsigned short*)C)[idx]=f2bf(acc[g][nt][r]);
        else   ((float*)C)[idx]=acc[g][nt][r];
      }
}

// ---- causal depthwise conv(K=4)+bias -> SiLU ----
__global__ __launch_bounds__(256) void conv_act_k(const float* __restrict__ xin,
                                                  const float* __restrict__ ck,
                                                  const float* __restrict__ cb,
                                                  float* __restrict__ act){
  const int i=blockIdx.x*256+threadIdx.x;
  if(i>=(int)N_BSH) return;
  const int bs=i/H_, h=i-bs*H_;
  const int b=bs/S_, s=bs-b*S_;
  float xc=cb[h];
#pragma unroll
  for(int w=0;w<4;w++){
    const int sr=s-3+w;
    if(sr>=0) xc+=xin[(size_t)(b*S_+sr)*H2_+h]*ck[w*H_+h];
  }
  act[(size_t)bs*H_+h]=siluf(xc);
}

// ---- headwise q/k/v ----
__global__ __launch_bounds__(256) void qkv_k(const float* __restrict__ act,
                                             const float* __restrict__ xin,
                                             const float* __restrict__ Wq,
                                             const float* __restrict__ Wk,
                                             const float* __restrict__ Wv,
                                             float* __restrict__ qb,float* __restrict__ kb,
                                             float* __restrict__ vb){
  const int i=blockIdx.x*256+threadIdx.x;
  if(i>=(int)N_BSH) return;
  const int bs=i/H_, h=i-bs*H_;
  const int b=bs/S_, s=bs-b*S_;
  const int ph=h>>2, o=h&3, base=ph*4;
  float q=0.f,k=0.f,v=0.f;
#pragma unroll
  for(int d=0;d<4;d++){
    const float a=act[(size_t)bs*H_+base+d];
    const float x=xin[(size_t)bs*H2_+base+d];
    q+=a*Wq[ph*16+d*4+o];
    k+=a*Wk[ph*16+d*4+o];
    v+=x*Wv[ph*16+d*4+o];
  }
  const int nh=h/DH_, dh=h-nh*DH_;
  const size_t off=((size_t)(b*NH_+nh)*S_+s)*DH_+dh;
  qb[off]=q; kb[off]=k; vb[off]=v;
}

// ============================================================================
// gates v2 — one wave per (b,s) row. Coalesced q/k/v (read once, not 4x),
// float4 weight loads (all 4 gate heads per load), full-wave shfl reduce.
// ============================================================================
__global__ __launch_bounds__(256) void gates2_k(const float* __restrict__ qb,
                                                const float* __restrict__ kb,
                                                const float* __restrict__ vb,
                                                const float* __restrict__ Wig,
                                                const float* __restrict__ big,
                                                const float* __restrict__ Wfg,
                                                const float* __restrict__ bfg,
                                                float* __restrict__ igb,
                                                float* __restrict__ logfb){
  const int wid=(blockIdx.x*256+threadIdx.x)>>6;   // row = (b,s), 4096 waves
  const int l=threadIdx.x&63;
  if(wid>=BS_) return;
  const int b=wid>>11, s=wid&2047;
  float aI0=0.f,aI1=0.f,aI2=0.f,aI3=0.f;
  float aF0=0.f,aF1=0.f,aF2=0.f,aF3=0.f;
  for(int nh=0;nh<NH_;nh++){
    const size_t rb=((size_t)(b*NH_+nh)*S_+s)*DH_;
    const int hb=nh*DH_;
    for(int dh=l;dh<DH_;dh+=64){
      const int h=hb+dh;
      const float q=qb[rb+dh], k=kb[rb+dh], v=vb[rb+dh];
      const float4 wiq=*reinterpret_cast<const float4*>(&Wig[(size_t)h*4]);
      const float4 wik=*reinterpret_cast<const float4*>(&Wig[(size_t)(H_+h)*4]);
      const float4 wiv=*reinterpret_cast<const float4*>(&Wig[(size_t)(2*H_+h)*4]);
      const float4 wfq=*reinterpret_cast<const float4*>(&Wfg[(size_t)h*4]);
      const float4 wfk=*reinterpret_cast<const float4*>(&Wfg[(size_t)(H_+h)*4]);
      const float4 wfv=*reinterpret_cast<const float4*>(&Wfg[(size_t)(2*H_+h)*4]);
      aI0+=q*wiq.x+k*wik.x+v*wiv.x;
      aI1+=q*wiq.y+k*wik.y+v*wiv.y;
      aI2+=q*wiq.z+k*wik.z+v*wiv.z;
      aI3+=q*wiq.w+k*wik.w+v*wiv.w;
      aF0+=q*wfq.x+k*wfk.x+v*wfv.x;
      aF1+=q*wfq.y+k*wfk.y+v*wfv.y;
      aF2+=q*wfq.z+k*wfk.z+v*wfv.z;
      aF3+=q*wfq.w+k*wfk.w+v*wfv.w;
    }
  }
#pragma unroll
  for(int m=1;m<64;m<<=1){
    aI0+=__shfl_xor(aI0,m); aI1+=__shfl_xor(aI1,m);
    aI2+=__shfl_xor(aI2,m); aI3+=__shfl_xor(aI3,m);
    aF0+=__shfl_xor(aF0,m); aF1+=__shfl_xor(aF1,m);
    aF2+=__shfl_xor(aF2,m); aF3+=__shfl_xor(aF3,m);
  }
  if(l==0){
    const size_t o0=(size_t)(b*NH_+0)*S_+s;
    const size_t o1=(size_t)(b*NH_+1)*S_+s;
    const size_t o2=(size_t)(b*NH_+2)*S_+s;
    const size_t o3=(size_t)(b*NH_+3)*S_+s;
    igb[o0]=aI0+big[0]; igb[o1]=aI1+big[1];
    igb[o2]=aI2+big[2]; igb[o3]=aI3+big[3];
    logfb[o0]=logsigf(aF0+bfg[0]); logfb[o1]=logsigf(aF1+bfg[1]);
    logfb[o2]=logsigf(aF2+bfg[2]); logfb[o3]=logsigf(aF3+bfg[3]);
  }
}

// ---- K prep: split fp32 K into hi/lo bf16, MFMA B-fragment tile layout ----
__global__ __launch_bounds__(256) void kprep_k(const float* __restrict__ kb,
                                               unsigned short* __restrict__ khi,
                                               unsigned short* __restrict__ klo){
  const int blk=blockIdx.x;                 // 8 heads * 128 t-tiles
  const int head=blk>>7, tt=blk&127;
  const size_t obase=(size_t)blk*11*512;
  for(int slot=threadIdx.x; slot<704; slot+=256){
    const int dc=slot>>6, ll=slot&63, quad=ll>>4, lm=ll&15;
    const int tg=tt*16+lm, dbase=dc*32+quad*8;
    float v[8];
    if(dbase<336){
      load4(&kb[((size_t)head*S_+tg)*DH_+dbase],v);
      load4(&kb[((size_t)head*S_+tg)*DH_+dbase+4],v+4);
    } else { for(int j=0;j<8;j++) v[j]=0.f; }
    unsigned short hi8[8], lo8[8];
#pragma unroll
    for(int j=0;j<8;j++){
      hi8[j]=f2bf(v[j]);
      lo8[j]=f2bf(v[j]-bf2f(hi8[j]));
    }
    const size_t o=obase+(size_t)(dc*64+ll)*8;
    uint4 ph, pl;
    ph.x=(unsigned)hi8[0]|((unsigned)hi8[1]<<16); ph.y=(unsigned)hi8[2]|((unsigned)hi8[3]<<16);
    ph.z=(unsigned)hi8[4]|((unsigned)hi8[5]<<16); ph.w=(unsigned)hi8[6]|((unsigned)hi8[7]<<16);
    pl.x=(unsigned)lo8[0]|((unsigned)lo8[1]<<16); pl.y=(unsigned)lo8[2]|((unsigned)lo8[3]<<16);
    pl.z=(unsigned)lo8[4]|((unsigned)lo8[5]<<16); pl.w=(unsigned)lo8[6]|((unsigned)lo8[7]<<16);
    *reinterpret_cast<uint4*>(&khi[o])=ph;
    *reinterpret_cast<uint4*>(&klo[o])=pl;
  }
}

// ---- V prep: V^T bf16 in MFMA B-fragment tile layout; col 336 = ones ----
__global__ __launch_bounds__(256) void vprep_k(const float* __restrict__ vb,
                                               unsigned short* __restrict__ vTf){
  const int blk=blockIdx.x;                 // 8 heads * 64 t-chunks
  const int head=blk>>6, tc=blk&63;
  const size_t obase=(size_t)blk*22*512;
  for(int slot=threadIdx.x; slot<1408; slot+=256){
    const int ntg=slot>>6, ll=slot&63, quad=ll>>4, lm=ll&15;
    const int n=ntg*16+lm, t0=tc*32+quad*8;
    unsigned short h8[8];
#pragma unroll
    for(int j=0;j<8;j++){
      float val;
      if(n<336)       val=vb[((size_t)head*S_+t0+j)*DH_+n];
      else if(n==336) val=1.f;
      else            val=0.f;
      h8[j]=f2bf(val);
    }
    uint4 pk;
    pk.x=(unsigned)h8[0]|((unsigned)h8[1]<<16); pk.y=(unsigned)h8[2]|((unsigned)h8[3]<<16);
    pk.z=(unsigned)h8[4]|((unsigned)h8[5]<<16); pk.w=(unsigned)h8[6]|((unsigned)h8[7]<<16);
    *reinterpret_cast<uint4*>(&vTf[obase+(size_t)(ntg*64+ll)*8])=pk;
  }
}

// ---- parallel per-head scan ----
__global__ __launch_bounds__(256) void scan_k(const float* __restrict__ igb,
                                              const float* __restrict__ logfb,
                                              float* __restrict__ ab,float* __restrict__ Mb,
                                              float* __restrict__ mtb){
  const int head=blockIdx.x, t=threadIdx.x;
  __shared__ float sh[256];
  const float* lf=logfb+(size_t)head*S_;
  const float* ig=igb+(size_t)head*S_;
  float lc[8];
  float run=0.f;
#pragma unroll
  for(int i=0;i<8;i++){ run+=lf[t*8+i]; lc[i]=run; }
  sh[t]=run;
  for(int st=1;st<256;st<<=1){
    __syncthreads();
    const float v=(t>=st)?sh[t-st]:0.f;
    __syncthreads();
    sh[t]+=v;
  }
  __syncthreads();
  const float off=(t==0)?0.f:sh[t-1];
  __syncthreads();
  float av[8],mv[8],cv[8];
  float mrun=-1e30f;
#pragma unroll
  for(int i=0;i<8;i++){
    cv[i]=off+lc[i];
    av[i]=ig[t*8+i]-cv[i];
    mrun=fmaxf(mrun,av[i]);
    mv[i]=mrun;
  }
  sh[t]=mrun;
  for(int st=1;st<256;st<<=1){
    __syncthreads();
    const float v=(t>=st)?sh[t-st]:-1e30f;
    __syncthreads();
    sh[t]=fmaxf(sh[t],v);
  }
  __syncthreads();
  const float moff=(t==0)?-1e30f:sh[t-1];
#pragma unroll
  for(int i=0;i<8;i++){
    const float Mi=fmaxf(moff,mv[i]);
    const size_t j=(size_t)head*S_+t*8+i;
    ab[j]=av[i]; Mb[j]=Mi; mtb[j]=cv[i]+Mi;
  }
}

// ============================================================================
// mLSTM v9 — paired supertiles + global_load_lds DMA staging (passing).
// ============================================================================
__global__ __launch_bounds__(256,1) void mlstm4_k(
    const float* __restrict__ qb, const unsigned short* __restrict__ khi,
    const unsigned short* __restrict__ klo, const unsigned short* __restrict__ vTf,
    const float* __restrict__ ab, const float* __restrict__ Mb,
    float* __restrict__ part, float* __restrict__ rsum){
  const int bid=blockIdx.x;
  const int head=bid&7;                     // XCD pin: head h -> XCD h
  const int rest=bid>>3;                    // 0..31
  const int pairI=rest>>1, seg=rest&1;
  const int t=threadIdx.x, w=t>>6, l=t&63, lm=l&15, quad=l>>4;

  // LDS: double-buffered chunk staging (66 frag-tiles of 512 shorts each)
  // layout per buffer: [0..21]=khi(2tt x 11dc), [22..43]=klo, [44..65]=vTf
  __shared__ short KV[2][66*512];
  __shared__ short Sc[4][16][40];

  const size_t hb=(size_t)head*S_;
  const float scale=0.05455447256f;         // 336^-0.5

  const int sbA=pairI, sbB=31-pairI;
  const int nA=sbA+1, nTot=33;              // uniform work across all blocks

  bf16x8 qh[11], ql[11];
  f32x4 accO[22];
  float Mr[4];
  int ws0=sbA*64+w*16;

  auto loadQ=[&](int ws0_){
    const float* qrow=qb+(hb+ws0_+lm)*DH_;
#pragma unroll
    for(int dc=0;dc<11;dc++){
      const int dbase=dc*32+quad*8;
      float v[8];
      if(dbase<336){ load4(qrow+dbase,v); load4(qrow+dbase+4,v+4); }
      else { for(int j=0;j<8;j++) v[j]=0.f; }
#pragma unroll
      for(int j=0;j<8;j++){
        const unsigned short h=f2bf(v[j]);
        qh[dc][j]=(short)h;
        ql[dc][j]=(short)f2bf(v[j]-bf2f(h));
      }
    }
#pragma unroll
    for(int r=0;r<4;r++) Mr[r]=Mb[hb+ws0_+quad*4+r];
#pragma unroll
    for(int n=0;n<22;n++) accO[n]={0.f,0.f,0.f,0.f};
  };

  // item i -> chunk index c (32-col chunks)
  auto itemC=[&](int i)->int{
    return (i<nA)? (seg+2*i) : (seg+2*(i-nA));
  };

  // direct global->LDS DMA: per frag-tile, 64 lanes x 16B = 1024B.
  auto stage=[&](int buf,int c){
    const size_t kbase=(((size_t)head*128+(size_t)(2*c))*11)*512+(size_t)l*8;
    const size_t vbase=(((size_t)head*64+(size_t)c)*22)*512+(size_t)l*8;
#pragma unroll
    for(int j=0;j<17;j++){
      const int tr=w+4*j;
      if(tr<66){
        const unsigned short* src;
        if(tr<22)      src=&khi[kbase+(size_t)tr*512];
        else if(tr<44) src=&klo[kbase+(size_t)(tr-22)*512];
        else           src=&vTf[vbase+(size_t)(tr-44)*512];
        __builtin_amdgcn_global_load_lds(
          (const __attribute__((address_space(1))) unsigned int*)src,
          (__attribute__((address_space(3))) unsigned int*)&KV[buf][(size_t)tr*512],
          16,0,0);
      }
    }
  };

  auto compute=[&](int c,int buf){
    const int t0=c<<5;
    const float al0=ab[hb+t0+lm];
    const float al1=ab[hb+t0+16+lm];
#pragma unroll
    for(int tt=0;tt<2;tt++){
      f32x4 a0={0,0,0,0}, a1={0,0,0,0}, a2={0,0,0,0};
#pragma unroll
      for(int dc=0;dc<11;dc++){
        const bf16x8 kh=*reinterpret_cast<const bf16x8*>(&KV[buf][(tt*11+dc)*512+l*8]);
        const bf16x8 kl=*reinterpret_cast<const bf16x8*>(&KV[buf][(22+tt*11+dc)*512+l*8]);
        a0=__builtin_amdgcn_mfma_f32_16x16x32_bf16(qh[dc],kh,a0,0,0,0);
        a1=__builtin_amdgcn_mfma_f32_16x16x32_bf16(ql[dc],kh,a1,0,0,0);
        a2=__builtin_amdgcn_mfma_f32_16x16x32_bf16(qh[dc],kl,a2,0,0,0);
      }
      const float al=(tt==0)?al0:al1;
      const int tg=t0+tt*16+lm;
#pragma unroll
      for(int r=0;r<4;r++){
        const int srow=quad*4+r;
        const float qk=a0[r]+a1[r]+a2[r];
        const float e=fminf(al-Mr[r],0.f);
        const float msk=(tg<=ws0+srow)?1.f:0.f;
        Sc[w][srow][tt*16+lm]=(short)f2bf(msk*(qk*scale*expf(e)));
      }
    }
    const bf16x8 scf=*reinterpret_cast<const bf16x8*>(&Sc[w][lm][quad*8]);
#pragma unroll
    for(int nt=0;nt<22;nt++){
      const bf16x8 vf=*reinterpret_cast<const bf16x8*>(&KV[buf][(44+nt)*512+l*8]);
      accO[nt]=__builtin_amdgcn_mfma_f32_16x16x32_bf16(scf,vf,accO[nt],0,0,0);
    }
  };

  auto epilogue=[&](){
    const size_t pbase=(size_t)head*2048+ws0;
#pragma unroll
    for(int nt=0;nt<22;nt++){
      const int col=nt*16+lm;
#pragma unroll
      for(int r=0;r<4;r++){
        const int srow=quad*4+r;
        const float val=accO[nt][r];
        if(col<336){ if(val!=0.f) atomicAdd(&part[(pbase+srow)*336+col],val); }
        else if(col==336){ if(val!=0.f) atomicAdd(&rsum[pbase+srow],val); }
      }
    }
  };

  loadQ(ws0);
  stage(0,itemC(0));
  __syncthreads();                          // drains vmcnt: buffer 0 ready
  int cur=0;
  for(int i=0;i<nTot;i++){
    if(i+1<nTot) stage(cur^1,itemC(i+1));   // DMA next chunk into back buffer
    compute(itemC(i),cur);
    if(i==nA-1){                            // tile switch: A done
      epilogue();
      ws0=sbB*64+w*16;
      loadQ(ws0);
    }
    __syncthreads();                        // drain DMA + cross-wave sync
    cur^=1;
  }
  epilogue();                               // tile B
}

// ============================================================================
// finalize: n-normalizer + per-head groupnorm + hout write (v6, proven).
// ============================================================================
__global__ __launch_bounds__(256) void finalize_k(const float* __restrict__ part,
                                                  const float* __restrict__ rsum,
                                                  const float* __restrict__ mtb,
                                                  const float* __restrict__ lnw,
                                                  float* __restrict__ hout){
  const int sblk=blockIdx.x, head=blockIdx.y;
  const int bI=head>>2, nh=head&3;
  const int s0=sblk*32;
  const int t=threadIdx.x, row=t>>3, sub=t&7;
  __shared__ float red1[32][8], red2[32][8];
  __shared__ float mu_s[32], rs_s[32], inv_s[32];
  const size_t pbase=(size_t)head*2048+s0;
  const float* prow=part+(pbase+row)*336;
  float s1=0.f,s2=0.f;
  for(int c=sub;c<336;c+=8){ const float v=prow[c]; s1+=v; s2+=v*v; }
  red1[row][sub]=s1; red2[row][sub]=s2;
  __syncthreads();
  if(sub==0){
    float a1=0.f,a2=0.f;
#pragma unroll
    for(int j=0;j<8;j++){ a1+=red1[row][j]; a2+=red2[row][j]; }
    const float mt=mtb[(size_t)head*S_+s0+row];
    const float nn=fmaxf(fabsf(rsum[pbase+row]), expf(fminf(fmaxf(-mt,-60.f),60.f)));
    const float inv=1.f/(nn+1e-6f);
    const float mu=a1*inv/336.f;
    const float var=a2*inv*inv/336.f-mu*mu;
    inv_s[row]=inv; mu_s[row]=mu;
    rs_s[row]=rsqrtf(fmaxf(var,0.f)+1e-5f);
  }
  __syncthreads();
  const float inv=inv_s[row], mu=mu_s[row], rs=rs_s[row];
  float* orow=hout+((size_t)(bI*S_+s0+row))*H_+nh*DH_;
  for(int c=sub;c<336;c+=8)
    orow[c]=(prow[c]*inv-mu)*rs*lnw[nh*DH_+c];
}

// ---- h_state = (h_out + skip*act) * silu(z) ----
__global__ __launch_bounds__(256) void hstate_k(const float* __restrict__ hout,
                                                const float* __restrict__ act,
                                                const float* __restrict__ xin,
                                                const float* __restrict__ skip,
                                                float* __restrict__ hs){
  const int i=blockIdx.x*256+threadIdx.x;
  if(i>=(int)N_BSH) return;
  const int bs=i/H_, h=i-bs*H_;
  const float z=xin[(size_t)bs*H2_+H_+h];
  hs[(size_t)bs*H_+h]=(hout[(size_t)bs*H_+h]+skip[h]*act[(size_t)bs*H_+h])*siluf(z);
}

// ============================================================================
extern "C" void kernel_launch(void* const* d_in, const int* in_sizes, int n_in,
                              void* d_out, int out_size, void* d_ws, size_t ws_size,
                              hipStream_t stream){
  float* ws=(float*)d_ws;
  int* flag=(int*)ws;

  float* igb  = ws+O_IGB;
  float* logfb= ws+O_LOGF;
  float* ab   = ws+O_AB;
  float* Mbuf = ws+O_MB;
  float* mtb  = ws+O_MTB;
  float* f_ck = ws+O_CK;
  float* f_cb = ws+O_CB;
  float* f_wq = ws+O_WQ;
  float* f_wk = ws+O_WK;
  float* f_wv = ws+O_WV;
  float* f_wig= ws+O_WIG;
  float* f_big= ws+O_BIG;
  float* f_wfg= ws+O_WFG;
  float* f_bfg= ws+O_BFG;
  float* f_lnw= ws+O_LNW;
  float* f_skp= ws+O_SKP;
  float* xin  = ws+O_XIN;
  float* act  = ws+O_ACT;
  float* qb   = ws+O_QB;
  float* kb   = ws+O_KB;
  float* vb   = ws+O_VB;
  float* hout = ws+O_HOUT;
  float* hs   = qb;                            // alias: q dead after mlstm4_k

  unsigned short* xhi  =(unsigned short*)(ws+O_FX);   unsigned short* xlo  =xhi+N_X;
  unsigned short* wuphi=(unsigned short*)(ws+O_FWUP); unsigned short* wuplo=wuphi+N_WUP;
  unsigned short* wdnhi=(unsigned short*)(ws+O_FWDN); unsigned short* wdnlo=wdnhi+N_WDN;
  unsigned short* khi=(unsigned short*)(ws+O_FX);     // x/wup frags dead after up-gemm
  unsigned short* klo=khi+KSPLIT_SHORTS;
  unsigned short* vTf=(unsigned short*)kb;     // kb dead after gates+kprep
  unsigned short* hshi=(unsigned short*)kb;    // vTf dead after mlstm4_k
  unsigned short* hslo=hshi+N_BSH;
  float* partb=vb;                             // vb dead after vprep
  float* rsumb=igb;                            // igb dead after scan_k

  detect_k<<<1,256,0,stream>>>((const unsigned short*)d_in[0],flag);
  auto cvt=[&](int idx,float* dst,size_t n){
    convert_k<<<(int)((n+255)/256),256,0,stream>>>(d_in[idx],dst,(int)n,flag);
  };
  cvt(2,f_ck,N_CK);  cvt(3,f_cb,H_);
  cvt(4,f_wq,N_WH); cvt(5,f_wk,N_WH);   cvt(6,f_wv,N_WH);  cvt(7,f_wig,N_WG);
  cvt(8,f_big,4);   cvt(9,f_wfg,N_WG);  cvt(10,f_bfg,4);   cvt(11,f_lnw,H_);
  cvt(12,f_skp,H_);

  // up-GEMM: xin = x @ Wup  (M=4096,K=1024 kcn=32, N=2688)
  aprep_k<<<(256*32*64+255)/256,256,0,stream>>>(d_in[0],flag,32,1024,256*32*64,xhi,xlo);
  bprep_k<<<(168*32*64+255)/256,256,0,stream>>>(d_in[1],flag,32,2688,168*32*64,wuphi,wuplo);
  gemm_mfma_k<<<dim3(2688/64,4096/128),256,0,stream>>>(xhi,xlo,wuphi,wuplo,xin,nullptr,32,H2_);

  conv_act_k<<<(int)((N_BSH+255)/256),256,0,stream>>>(xin,f_ck,f_cb,act);
  qkv_k<<<(int)((N_BSH+255)/256),256,0,stream>>>(act,xin,f_wq,f_wk,f_wv,qb,kb,vb);
  // gates v2: one wave per (b,s) row, 4096 waves
  gates2_k<<<(BS_*64+255)/256,256,0,stream>>>(qb,kb,vb,f_wig,f_big,f_wfg,f_bfg,igb,logfb);
  kprep_k<<<8*128,256,0,stream>>>(kb,khi,klo);
  vprep_k<<<8*64,256,0,stream>>>(vb,vTf);
  // wdn frags (independent; region untouched by khi/klo)
  bprep_k<<<(64*42*64+255)/256,256,0,stream>>>(d_in[13],flag,42,1024,64*42*64,wdnhi,wdnlo);
  scan_k<<<B_*NH_,256,0,stream>>>(igb,logfb,ab,Mbuf,mtb);
  hipMemsetAsync(partb,0,N_BSH*sizeof(float),stream);
  hipMemsetAsync(rsumb,0,(size_t)NG_*sizeof(float),stream);
  // mLSTM v9: 256 blocks = 8 heads x 16 pairs x 2 seg; 33 chunks/block uniform
  mlstm4_k<<<256,256,0,stream>>>(qb,khi,klo,vTf,ab,Mbuf,partb,rsumb);
  finalize_k<<<dim3(S_/32,B_*NH_),256,0,stream>>>(partb,rsumb,mtb,f_lnw,hout);
  hstate_k<<<(int)((N_BSH+255)/256),256,0,stream>>>(hout,act,xin,f_skp,hs);
  // down-GEMM: out = hs @ Wdn  (M=4096,K=1344 kcn=42, N=1024), direct to d_out
  aprep_k<<<(256*42*64+255)/256,256,0,stream>>>(hs,nullptr,42,1344,256*42*64,hshi,hslo);
  gemm_mfma_k<<<dim3(1024/64,4096/128),256,0,stream>>>(hshi,hslo,wdnhi,wdnlo,d_out,flag,42,E_);
}